// Round 1
// baseline (738.685 us; speedup 1.0000x reference)
//
#include <hip/hip_runtime.h>
#include <math.h>

// ============================================================================
// acsasrec_decode2: full disentangled-attention transformer layer, bf16 MFMA.
//
// Pipeline:
//   cast x/value/beha/pos -> bf16; transpose-cast weights to [N,K] bf16
//   PQh = 0.5*(pos@Wpq + bpq), PKh = 0.5*(pos@Wpk + bpk)           (f32 [S,H])
//   q = x@Wq+bq ; p = beha@(.5Wbq)+.5bbq+PQh[s]  -> Qt = [q+p | q] (bf16)
//   k = x@Wk+bk ; m = beha@(.5Wbk)+.5bbk+PKh[s]  -> Kt = [k | m]   (bf16)
//   v = value@Wv+bv+value  -> Vt [B,NH,64,S] (transposed for PV B-frags)
//   flash attention (dh'=128 scores, dh=64 PV), causal+padding mask, /8, -10000
//   attn_out = LN(ctx@Wd + bd + x)
//   out = LN(gelu(attn_out@W1+b1)@W2 + b2 + attn_out)
// ============================================================================

typedef unsigned short u16;
typedef __attribute__((ext_vector_type(8))) short bf16x8;
typedef __attribute__((ext_vector_type(4))) float f32x4;

#define NB 32
#define NS 512
#define HD 512
#define NM (NB*NS)      // 16384 tokens
#define NI 2048

__device__ __forceinline__ u16 f2b(float f) {
  union { float f; unsigned u; } x; x.f = f;
  return (u16)((x.u + 0x7fffu + ((x.u >> 16) & 1u)) >> 16);  // RNE
}

__device__ __forceinline__ f32x4 mfma16(bf16x8 a, bf16x8 b, f32x4 c) {
  return __builtin_amdgcn_mfma_f32_16x16x32_bf16(a, b, c, 0, 0, 0);
}

// ---------------- cast f32 -> bf16, float4-vectorized ----------------
__global__ __launch_bounds__(256) void cast_kernel(const float* __restrict__ in,
                                                   u16* __restrict__ out, int n4) {
  int i = blockIdx.x * 256 + threadIdx.x;
  if (i >= n4) return;
  float4 v = ((const float4*)in)[i];
  ((ushort4*)out)[i] = make_ushort4(f2b(v.x), f2b(v.y), f2b(v.z), f2b(v.w));
}

// ---------------- weight transpose+cast: W[K,N] f32 -> WT[N,K] bf16 ----------
struct W8Args { const float* w[8]; u16* o[8]; float sc[8]; };

__global__ __launch_bounds__(256) void wprep8_kernel(W8Args a) {
  __shared__ __align__(16) u16 til[64*72];
  const float* in = a.w[blockIdx.z];
  u16* out = a.o[blockIdx.z];
  float sc = a.sc[blockIdx.z];
  int n0 = blockIdx.x*64, k0 = blockIdx.y*64;
  for (int idx = threadIdx.x; idx < 4096; idx += 256) {
    int r = idx>>6, c = idx&63;
    til[r*72+c] = f2b(in[(k0+r)*512 + n0+c] * sc);
  }
  __syncthreads();
  for (int idx = threadIdx.x; idx < 4096; idx += 256) {
    int r = idx>>6, c = idx&63;
    out[(n0+r)*512 + k0+c] = til[c*72+r];
  }
}

__global__ __launch_bounds__(256) void wprep_kernel(const float* __restrict__ in,
                                                    u16* __restrict__ out, int K, int N) {
  __shared__ __align__(16) u16 til[64*72];
  int n0 = blockIdx.x*64, k0 = blockIdx.y*64;
  for (int idx = threadIdx.x; idx < 4096; idx += 256) {
    int r = idx>>6, c = idx&63;
    til[r*72+c] = f2b(in[(k0+r)*N + n0+c]);
  }
  __syncthreads();
  for (int idx = threadIdx.x; idx < 4096; idx += 256) {
    int r = idx>>6, c = idx&63;
    out[(n0+r)*K + k0+c] = til[c*72+r];
  }
}

__global__ void bias05_kernel(const float* a, const float* b, float* oa, float* ob) {
  int i = blockIdx.x*256 + threadIdx.x;
  if (i < 512) { oa[i] = 0.5f*a[i]; ob[i] = 0.5f*b[i]; }
}

// ---------------- GEMM: C = epi(A[M,K]bf16 @ WT[N,K]^T + bias) ----------------
// 128x128 tile, BK=32, 4 waves (2x2), 16x16x32 MFMA, 4x4 acc/wave.
// EPI: 0 plain | 1 (v+bias)*0.5 | 2 +extra[(gm%512)*N+gn] | 3 +extra[gm*N+gn]
//      4 gelu(v+bias).   OUTB: 0 f32, 1 bf16.
// Requires M%128==0, N%128==0, K%32==0 (true for all calls here).
template<int EPI, int OUTB>
__global__ __launch_bounds__(256, 2) void gemm_kernel(
    const u16* __restrict__ A, const u16* __restrict__ WT,
    const float* __restrict__ bias, const float* __restrict__ extra,
    void* __restrict__ outp, int M, int N, int K)
{
  __shared__ __align__(16) u16 As[128*40];   // +8 bf16 pad: 2-way-bank-free b128 reads
  __shared__ __align__(16) u16 Bs[128*40];
  const int tid = threadIdx.x;
  const int wave = tid>>6, lane = tid&63, quad = lane>>4, l16 = lane&15;
  const int wm = wave>>1, wn = wave&1;
  const int m0 = blockIdx.y*128, n0 = blockIdx.x*128;

  f32x4 acc[4][4] = {};

  const int r1 = tid>>2, ch1 = (tid&3)*8;        // 2 16B chunks/thread per tile
  const u16* pa0 = A  + (m0+r1)*K + ch1;
  const u16* pa1 = pa0 + 64*K;
  const u16* pb0 = WT + (n0+r1)*K + ch1;
  const u16* pb1 = pb0 + 64*K;
  u16* sa0 = &As[r1*40 + ch1];  u16* sa1 = &As[(r1+64)*40 + ch1];
  u16* sb0 = &Bs[r1*40 + ch1];  u16* sb1 = &Bs[(r1+64)*40 + ch1];

  for (int k0 = 0; k0 < K; k0 += 32) {
    uint4 a0 = *(const uint4*)(pa0 + k0);
    uint4 a1 = *(const uint4*)(pa1 + k0);
    uint4 b0 = *(const uint4*)(pb0 + k0);
    uint4 b1 = *(const uint4*)(pb1 + k0);
    *(uint4*)sa0 = a0; *(uint4*)sa1 = a1;
    *(uint4*)sb0 = b0; *(uint4*)sb1 = b1;
    __syncthreads();
    bf16x8 af[4], bf[4];
    #pragma unroll
    for (int i = 0; i < 4; ++i)
      af[i] = *(const bf16x8*)&As[(wm*64 + i*16 + l16)*40 + quad*8];
    #pragma unroll
    for (int j = 0; j < 4; ++j)
      bf[j] = *(const bf16x8*)&Bs[(wn*64 + j*16 + l16)*40 + quad*8];
    #pragma unroll
    for (int i = 0; i < 4; ++i)
      #pragma unroll
      for (int j = 0; j < 4; ++j)
        acc[i][j] = mfma16(af[i], bf[j], acc[i][j]);
    __syncthreads();
  }

  #pragma unroll
  for (int j = 0; j < 4; ++j) {
    int gn = n0 + wn*64 + j*16 + l16;
    float bv = bias[gn];
    #pragma unroll
    for (int i = 0; i < 4; ++i) {
      int gmb = m0 + wm*64 + i*16 + quad*4;
      #pragma unroll
      for (int r = 0; r < 4; ++r) {
        int gm = gmb + r;
        float v = acc[i][j][r] + bv;
        if (EPI == 1) v *= 0.5f;
        if (EPI == 2) v += extra[(gm & 511)*N + gn];
        if (EPI == 3) v += extra[gm*N + gn];
        if (EPI == 4) v = 0.5f*v*(1.0f + erff(v*0.70710678118654752f));
        if (OUTB) ((u16*)outp)[gm*N + gn] = f2b(v);
        else      ((float*)outp)[gm*N + gn] = v;
      }
    }
  }
}

// ---------------- Qt/Kt builders ----------------
// mode 0: out = [a+b | a]  (Qt = [q+p | q]);  mode 1: out = [a | b] (Kt = [k | m])
__global__ __launch_bounds__(256) void build_qk_kernel(
    const float* __restrict__ aa, const float* __restrict__ bb2,
    u16* __restrict__ out, int mode)
{
  int gid = blockIdx.x*256 + threadIdx.x;          // over NM*HD
  int gm = gid >> 9, col = gid & 511;
  int h = col >> 6, d = col & 63;
  int b = gm >> 9, s = gm & 511;
  float av = aa[gid], bv = bb2[gid];
  int base = ((b*8 + h)*512 + s)*128 + d;
  out[base]      = f2b(mode ? av : av + bv);
  out[base + 64] = f2b(mode ? bv : av);
}

// ---------------- V reorder: [M,512] f32 -> [B,8,64,S] bf16 (d-major) --------
__global__ __launch_bounds__(256) void reorder_v_kernel(
    const float* __restrict__ vr, u16* __restrict__ out)
{
  __shared__ __align__(16) u16 til[64*72];
  int s0 = blockIdx.x*64;
  int bh = blockIdx.y, b = bh >> 3, h = bh & 7;
  for (int idx = threadIdx.x; idx < 4096; idx += 256) {
    int r = idx>>6, c = idx&63;                    // r=s-local, c=d
    til[r*72+c] = f2b(vr[(b*512 + s0 + r)*512 + h*64 + c]);
  }
  __syncthreads();
  for (int idx = threadIdx.x; idx < 4096; idx += 256) {
    int r = idx>>6, c = idx&63;                    // r=d, c=s-local
    out[((b*8 + h)*64 + r)*512 + s0 + c] = til[c*72 + r];
  }
}

// ---------------- flash attention ----------------
// grid (qt=8, h=8, b=32); 4 waves; wave owns 16 q-rows; 64-row k-tiles.
// Qt/Kt: [B,8,S,128] bf16; Vt: [B,8,64,S] bf16; ctx out: [M,512] bf16.
__global__ __launch_bounds__(256, 2) void attn_kernel(
    const u16* __restrict__ Qt, const u16* __restrict__ Kt,
    const u16* __restrict__ Vt, const int* __restrict__ iseq,
    u16* __restrict__ ctx)
{
  const int qt = blockIdx.x, h = blockIdx.y, b = blockIdx.z;
  const int tid = threadIdx.x;
  const int wave = tid >> 6, lane = tid & 63, quad = lane >> 4, l16 = lane & 15;

  __shared__ __align__(16) u16 Qs[64*136];   // [s][128] +8 pad
  __shared__ __align__(16) u16 Ks[64*136];
  __shared__ __align__(16) u16 Vs[64*72];    // [d][64 s] +8 pad
  __shared__ __align__(16) u16 Ps[4*16*72];  // per-wave P, [16 q][64 k] +8 pad
  __shared__ u16 validS[512];

  const int q0 = qt * 64;
  const u16* Qg = Qt + (size_t)((b*8 + h)*512) * 128;
  const u16* Kg = Kt + (size_t)((b*8 + h)*512) * 128;
  const u16* Vg = Vt + (size_t)((b*8 + h)*64) * 512;

  for (int i = tid; i < 512; i += 256) validS[i] = (u16)(iseq[b*512 + i] > 0);
  for (int c = tid; c < 1024; c += 256) {
    int r = c >> 4, ch = (c & 15) * 8;
    *(uint4*)&Qs[r*136 + ch] = *(const uint4*)&Qg[(q0 + r)*128 + ch];
  }
  __syncthreads();

  f32x4 Ob[4] = {};
  float mrow[4] = {-1e30f, -1e30f, -1e30f, -1e30f};
  float lrow[4] = {0.f, 0.f, 0.f, 0.f};
  const int qrow_base = q0 + wave*16 + quad*4;
  u16* Pw = &Ps[wave * (16*72)];

  for (int kt = 0; kt <= qt; ++kt) {           // causal: skip future tiles (exact)
    const int k0 = kt * 64;
    __syncthreads();                           // prior iter's Ks/Vs reads done
    for (int c = tid; c < 1024; c += 256) {
      int r = c >> 4, ch = (c & 15) * 8;
      *(uint4*)&Ks[r*136 + ch] = *(const uint4*)&Kg[(k0 + r)*128 + ch];
    }
    for (int c = tid; c < 512; c += 256) {
      int d = c >> 3, ch = (c & 7) * 8;
      *(uint4*)&Vs[d*72 + ch] = *(const uint4*)&Vg[d*512 + k0 + ch];
    }
    __syncthreads();

    // S-tile = Qs(16 rows) @ Ks^T : dh'=128 -> 4 MFMA k-steps
    f32x4 sc[4] = {};
    #pragma unroll
    for (int ks = 0; ks < 4; ++ks) {
      bf16x8 aq = *(const bf16x8*)&Qs[(wave*16 + l16)*136 + ks*32 + quad*8];
      #pragma unroll
      for (int j = 0; j < 4; ++j) {
        bf16x8 bk = *(const bf16x8*)&Ks[(j*16 + l16)*136 + ks*32 + quad*8];
        sc[j] = mfma16(aq, bk, sc[j]);
      }
    }

    // scale 1/sqrt(64), mask (causal & item_seq>0): +(-10000) like reference
    #pragma unroll
    for (int j = 0; j < 4; ++j) {
      int col = k0 + j*16 + l16;
      bool okc = (validS[col] != 0);
      #pragma unroll
      for (int r = 0; r < 4; ++r) {
        float s = sc[j][r] * 0.125f;
        sc[j][r] = (okc && col <= qrow_base + r) ? s : s - 10000.0f;
      }
    }

    // online softmax per q-row (row lives on 16 lanes sharing quad)
    float alpha[4], pj[4][4];
    #pragma unroll
    for (int r = 0; r < 4; ++r) {
      float mx = fmaxf(fmaxf(sc[0][r], sc[1][r]), fmaxf(sc[2][r], sc[3][r]));
      #pragma unroll
      for (int d2 = 1; d2 < 16; d2 <<= 1) mx = fmaxf(mx, __shfl_xor(mx, d2, 64));
      float mn = fmaxf(mrow[r], mx);
      alpha[r] = __expf(mrow[r] - mn);
      mrow[r] = mn;
      float s0 = 0.f;
      #pragma unroll
      for (int j = 0; j < 4; ++j) { float p = __expf(sc[j][r] - mn); pj[j][r] = p; s0 += p; }
      #pragma unroll
      for (int d2 = 1; d2 < 16; d2 <<= 1) s0 += __shfl_xor(s0, d2, 64);
      lrow[r] = lrow[r]*alpha[r] + s0;
    }
    #pragma unroll
    for (int c = 0; c < 4; ++c)
      #pragma unroll
      for (int r = 0; r < 4; ++r) Ob[c][r] *= alpha[r];

    // P: C-layout -> LDS -> A-operand layout (same wave; in-order LDS, no barrier)
    #pragma unroll
    for (int j = 0; j < 4; ++j)
      #pragma unroll
      for (int r = 0; r < 4; ++r)
        Pw[(quad*4 + r)*72 + j*16 + l16] = f2b(pj[j][r]);

    // O += P[16x64] @ V[64x64]
    #pragma unroll
    for (int c = 0; c < 4; ++c) {
      #pragma unroll
      for (int k2 = 0; k2 < 2; ++k2) {
        bf16x8 ap = *(const bf16x8*)&Pw[l16*72 + k2*32 + quad*8];
        bf16x8 bv = *(const bf16x8*)&Vs[(c*16 + l16)*72 + k2*32 + quad*8];
        Ob[c] = mfma16(ap, bv, Ob[c]);
      }
    }
  }

  #pragma unroll
  for (int r = 0; r < 4; ++r) {
    float inv = 1.0f / lrow[r];                // >= 1 always (max element)
    int grow = b*512 + qrow_base + r;
    #pragma unroll
    for (int c = 0; c < 4; ++c)
      ctx[(size_t)grow*512 + h*64 + c*16 + l16] = f2b(Ob[c][r] * inv);
  }
}

// ---------------- LayerNorm over H=512, one wave per row ----------------
__global__ __launch_bounds__(256) void ln_kernel(
    const float* __restrict__ a, const float* __restrict__ res,
    const float* __restrict__ g, const float* __restrict__ be,
    float* __restrict__ of, u16* __restrict__ ob)
{
  const int wave = threadIdx.x >> 6, lane = threadIdx.x & 63;
  const int row = blockIdx.x*4 + wave;
  const float4* pa = (const float4*)(a + (size_t)row*512);
  const float4* pr = (const float4*)(res + (size_t)row*512);
  float4 v0 = pa[lane], v1 = pa[lane+64];
  float4 r0 = pr[lane], r1 = pr[lane+64];
  v0.x += r0.x; v0.y += r0.y; v0.z += r0.z; v0.w += r0.w;
  v1.x += r1.x; v1.y += r1.y; v1.z += r1.z; v1.w += r1.w;
  float s = v0.x+v0.y+v0.z+v0.w + v1.x+v1.y+v1.z+v1.w;
  float q = v0.x*v0.x+v0.y*v0.y+v0.z*v0.z+v0.w*v0.w
          + v1.x*v1.x+v1.y*v1.y+v1.z*v1.z+v1.w*v1.w;
  #pragma unroll
  for (int d = 1; d < 64; d <<= 1) { s += __shfl_xor(s, d, 64); q += __shfl_xor(q, d, 64); }
  float mean = s * (1.0f/512.0f);
  float var  = q * (1.0f/512.0f) - mean*mean;
  float rstd = rsqrtf(var + 1e-12f);
  float4 g0 = ((const float4*)g)[lane],  g1 = ((const float4*)g)[lane+64];
  float4 b0 = ((const float4*)be)[lane], b1 = ((const float4*)be)[lane+64];
  float4 o0, o1;
  o0.x = (v0.x-mean)*rstd*g0.x + b0.x;  o0.y = (v0.y-mean)*rstd*g0.y + b0.y;
  o0.z = (v0.z-mean)*rstd*g0.z + b0.z;  o0.w = (v0.w-mean)*rstd*g0.w + b0.w;
  o1.x = (v1.x-mean)*rstd*g1.x + b1.x;  o1.y = (v1.y-mean)*rstd*g1.y + b1.y;
  o1.z = (v1.z-mean)*rstd*g1.z + b1.z;  o1.w = (v1.w-mean)*rstd*g1.w + b1.w;
  ((float4*)(of + (size_t)row*512))[lane]    = o0;
  ((float4*)(of + (size_t)row*512))[lane+64] = o1;
  if (ob) {
    ((ushort4*)(ob + (size_t)row*512))[lane]    = make_ushort4(f2b(o0.x), f2b(o0.y), f2b(o0.z), f2b(o0.w));
    ((ushort4*)(ob + (size_t)row*512))[lane+64] = make_ushort4(f2b(o1.x), f2b(o1.y), f2b(o1.z), f2b(o1.w));
  }
}

// ============================================================================
extern "C" void kernel_launch(void* const* d_in, const int* in_sizes, int n_in,
                              void* d_out, int out_size, void* d_ws, size_t ws_size,
                              hipStream_t stream) {
  (void)in_sizes; (void)n_in; (void)out_size; (void)ws_size;
  const float* x    = (const float*)d_in[0];
  const float* vin  = (const float*)d_in[1];
  const float* beh  = (const float*)d_in[2];
  const float* pos  = (const float*)d_in[3];
  const float* bq   = (const float*)d_in[5];
  const float* bk   = (const float*)d_in[7];
  const float* bv   = (const float*)d_in[9];
  const float* bpk  = (const float*)d_in[11];
  const float* bpq  = (const float*)d_in[13];
  const float* bbk  = (const float*)d_in[15];
  const float* bbq  = (const float*)d_in[17];
  const float* bd   = (const float*)d_in[19];
  const float* ln_g = (const float*)d_in[20];
  const float* ln_b = (const float*)d_in[21];
  const float* b1   = (const float*)d_in[23];
  const float* b2   = (const float*)d_in[25];
  const float* ln2_g= (const float*)d_in[26];
  const float* ln2_b= (const float*)d_in[27];
  const int*   iseq = (const int*)d_in[28];
  float* out = (float*)d_out;
  char* ws = (char*)d_ws;

  // ---- workspace layout (~196 MB), liveness-based aliasing documented ----
  size_t off = 0;
  auto nxt = [&](size_t sz) { size_t r = off; off += (sz + 255) & ~(size_t)255; return r; };
  size_t oWT[8]; for (int i = 0; i < 8; ++i) oWT[i] = nxt(512*512*2);
  size_t oW1T = nxt((size_t)512*2048*2);
  size_t oW2T = nxt((size_t)512*2048*2);
  size_t oBk5 = nxt(512*4);
  size_t oBq5 = nxt(512*4);
  size_t oPb  = nxt(512*512*2);
  size_t oPK  = nxt(512*512*4);
  size_t oPQ  = nxt(512*512*4);
  size_t oXb  = nxt((size_t)NM*512*2);   // xb; dead after kraw -> reused as attn_out bf16
  size_t oVb  = nxt((size_t)NM*512*2);   // vb; dead after vraw -> reused as ctx bf16
  size_t oBb  = nxt((size_t)NM*512*2);   // bb; dead after mraw -> reused as Vt
  size_t oR0  = nxt((size_t)NM*512*4);   // q/k/v-raw, attn_raw, h2
  size_t oR1  = nxt((size_t)NM*512*4);   // p/m-raw, attn_out f32
  size_t oQt  = nxt((size_t)33554432);   // Qt; Qt+Kt reused as h1 (64MB) after attention
  size_t oKt  = nxt((size_t)33554432);   // contiguous with oQt (sizes 256-aligned)

  u16* WT[8]; for (int i = 0; i < 8; ++i) WT[i] = (u16*)(ws + oWT[i]);
  u16*   W1T  = (u16*)(ws + oW1T);
  u16*   W2T  = (u16*)(ws + oW2T);
  float* Bbk5 = (float*)(ws + oBk5);
  float* Bbq5 = (float*)(ws + oBq5);
  u16*   posb = (u16*)(ws + oPb);
  float* PKh  = (float*)(ws + oPK);
  float* PQh  = (float*)(ws + oPQ);
  u16*   xb   = (u16*)(ws + oXb);
  u16*   vb   = (u16*)(ws + oVb);
  u16*   bb   = (u16*)(ws + oBb);
  float* R0   = (float*)(ws + oR0);
  float* R1   = (float*)(ws + oR1);
  u16*   Qtb  = (u16*)(ws + oQt);
  u16*   Ktb  = (u16*)(ws + oKt);
  u16*   Vtb  = (u16*)(ws + oBb);   // alias: bb dead
  u16*   Cb   = (u16*)(ws + oVb);   // alias: vb dead
  u16*   ab   = (u16*)(ws + oXb);   // alias: xb dead
  u16*   h1b  = (u16*)(ws + oQt);   // alias: Qt+Kt dead after attention

  // ---- prep: casts + weight transposes ----
  cast_kernel<<<8192, 256, 0, stream>>>(x,   xb, NM*512/4);
  cast_kernel<<<8192, 256, 0, stream>>>(vin, vb, NM*512/4);
  cast_kernel<<<8192, 256, 0, stream>>>(beh, bb, NM*512/4);
  cast_kernel<<<256,  256, 0, stream>>>(pos, posb, 512*512/4);
  W8Args wa;
  const int wi[8] = {4, 6, 8, 10, 12, 14, 16, 18};   // Wq Wk Wv Wpk Wpq Wbk Wbq Wd
  for (int i = 0; i < 8; ++i) {
    wa.w[i] = (const float*)d_in[wi[i]];
    wa.o[i] = WT[i];
    wa.sc[i] = (i == 5 || i == 6) ? 0.5f : 1.0f;     // Wbk, Wbq pre-scaled by 0.5
  }
  wprep8_kernel<<<dim3(8, 8, 8), 256, 0, stream>>>(wa);
  wprep_kernel<<<dim3(32, 8), 256, 0, stream>>>((const float*)d_in[22], W1T, 512, 2048);
  wprep_kernel<<<dim3(8, 32), 256, 0, stream>>>((const float*)d_in[24], W2T, 2048, 512);
  bias05_kernel<<<2, 256, 0, stream>>>(bbk, bbq, Bbk5, Bbq5);

  // ---- position projections: 0.5*(pos@W + b) ----
  gemm_kernel<1,0><<<dim3(4, 4), 256, 0, stream>>>(posb, WT[4], bpq, nullptr, PQh, 512, 512, 512);
  gemm_kernel<1,0><<<dim3(4, 4), 256, 0, stream>>>(posb, WT[3], bpk, nullptr, PKh, 512, 512, 512);

  // ---- Qt = [q+p | q] ----
  gemm_kernel<0,0><<<dim3(4, 128), 256, 0, stream>>>(xb, WT[0], bq,   nullptr, R0, NM, 512, 512);
  gemm_kernel<2,0><<<dim3(4, 128), 256, 0, stream>>>(bb, WT[6], Bbq5, PQh,     R1, NM, 512, 512);
  build_qk_kernel<<<32768, 256, 0, stream>>>(R0, R1, Qtb, 0);

  // ---- Kt = [k | m] ----
  gemm_kernel<0,0><<<dim3(4, 128), 256, 0, stream>>>(xb, WT[1], bk,   nullptr, R0, NM, 512, 512);
  gemm_kernel<2,0><<<dim3(4, 128), 256, 0, stream>>>(bb, WT[5], Bbk5, PKh,     R1, NM, 512, 512);
  build_qk_kernel<<<32768, 256, 0, stream>>>(R0, R1, Ktb, 1);

  // ---- V (+residual) -> transposed head layout ----
  gemm_kernel<3,0><<<dim3(4, 128), 256, 0, stream>>>(vb, WT[2], bv, vin, R0, NM, 512, 512);
  reorder_v_kernel<<<dim3(8, 256), 256, 0, stream>>>(R0, Vtb);

  // ---- attention ----
  attn_kernel<<<dim3(8, 8, 32), 256, 0, stream>>>(Qtb, Ktb, Vtb, iseq, Cb);

  // ---- output projection + LN1 (residual x) ----
  gemm_kernel<0,0><<<dim3(4, 128), 256, 0, stream>>>(Cb, WT[7], bd, nullptr, R0, NM, 512, 512);
  ln_kernel<<<4096, 256, 0, stream>>>(R0, x, ln_g, ln_b, R1, ab);

  // ---- FFN + LN2 (residual attn_out) ----
  gemm_kernel<4,1><<<dim3(16, 128), 256, 0, stream>>>(ab,  W1T, b1, nullptr, h1b, NM, 2048, 512);
  gemm_kernel<0,0><<<dim3(4, 128),  256, 0, stream>>>(h1b, W2T, b2, nullptr, R0,  NM, 512, 2048);
  ln_kernel<<<4096, 256, 0, stream>>>(R0, R1, ln2_g, ln2_b, out, nullptr);
}

// Round 2
// 659.769 us; speedup vs baseline: 1.1196x; 1.1196x over previous
//
#include <hip/hip_runtime.h>
#include <math.h>

// ============================================================================
// acsasrec_decode2 v2.
//  - GEMM: m97 structure (global_load_lds width=16, unpadded stride-32 LDS)
//  - Attention: 8-wave blocks (128 q-rows), Q-frags in regs, double-buffered
//    K/V with register prefetch (1 barrier/iter), wave-uniform causal skip.
//  - Fused epilogues: Qt/Kt interleave build, Vt transpose, gelu, biases.
//  - Qt pre-scaled by 0.125 (score scale folded in).
// ============================================================================

typedef unsigned short u16;
typedef __attribute__((ext_vector_type(8))) short bf16x8;
typedef __attribute__((ext_vector_type(4))) float f32x4;

#define NM 16384        // B*S tokens

__device__ __forceinline__ u16 f2b(float f) {
  union { float f; unsigned u; } x; x.f = f;
  return (u16)((x.u + 0x7fffu + ((x.u >> 16) & 1u)) >> 16);  // RNE
}
__device__ __forceinline__ float b2f(u16 u) {
  union { unsigned u; float f; } x; x.u = ((unsigned)u) << 16; return x.f;
}
__device__ __forceinline__ f32x4 mfma16(bf16x8 a, bf16x8 b, f32x4 c) {
  return __builtin_amdgcn_mfma_f32_16x16x32_bf16(a, b, c, 0, 0, 0);
}
// async global->LDS, 16B/lane. HW dest = wave-uniform base + lane*16, so the
// LDS pointer MUST be lane-contiguous in tid order (no padding!).
__device__ __forceinline__ void gl16(const u16* g, u16* l) {
  __builtin_amdgcn_global_load_lds(
      (const __attribute__((address_space(1))) unsigned int*)(const void*)g,
      (__attribute__((address_space(3))) unsigned int*)(void*)l, 16, 0, 0);
}

// ---------------- cast f32 -> bf16 ----------------
__global__ __launch_bounds__(256) void cast_kernel(const float* __restrict__ in,
                                                   u16* __restrict__ out, int n4) {
  int i = blockIdx.x * 256 + threadIdx.x;
  if (i >= n4) return;
  float4 v = ((const float4*)in)[i];
  ((ushort4*)out)[i] = make_ushort4(f2b(v.x), f2b(v.y), f2b(v.z), f2b(v.w));
}

// ---------------- weight transpose+cast: W[K,N] f32 -> WT[N,K] bf16 ----------
struct W8Args { const float* w[8]; u16* o[8]; float sc[8]; };

__global__ __launch_bounds__(256) void wprep8_kernel(W8Args a) {
  __shared__ __align__(16) u16 til[64*72];
  const float* in = a.w[blockIdx.z];
  u16* out = a.o[blockIdx.z];
  float sc = a.sc[blockIdx.z];
  int n0 = blockIdx.x*64, k0 = blockIdx.y*64;
  for (int idx = threadIdx.x; idx < 4096; idx += 256) {
    int r = idx>>6, c = idx&63;
    til[r*72+c] = f2b(in[(k0+r)*512 + n0+c] * sc);
  }
  __syncthreads();
  for (int idx = threadIdx.x; idx < 4096; idx += 256) {
    int r = idx>>6, c = idx&63;
    out[(n0+r)*512 + k0+c] = til[c*72+r];
  }
}

__global__ __launch_bounds__(256) void wprep_kernel(const float* __restrict__ in,
                                                    u16* __restrict__ out, int K, int N) {
  __shared__ __align__(16) u16 til[64*72];
  int n0 = blockIdx.x*64, k0 = blockIdx.y*64;
  for (int idx = threadIdx.x; idx < 4096; idx += 256) {
    int r = idx>>6, c = idx&63;
    til[r*72+c] = f2b(in[(k0+r)*N + n0+c]);
  }
  __syncthreads();
  for (int idx = threadIdx.x; idx < 4096; idx += 256) {
    int r = idx>>6, c = idx&63;
    out[(n0+r)*K + k0+c] = til[c*72+r];
  }
}

__global__ void bias05_kernel(const float* a, const float* b, float* oa, float* ob) {
  int i = blockIdx.x*256 + threadIdx.x;
  if (i < 512) { oa[i] = 0.5f*a[i]; ob[i] = 0.5f*b[i]; }
}

// ---------------- GEMM: C = epi(A[M,K]bf16 @ WT[N,K]^T + bias) ----------------
// 128x128 tile, BK=32, global_load_lds(16B) staging, unpadded stride-32 LDS.
// EPI: 0 plain->f32 | 1 (v+bias)*0.5 ->f32 | 4 gelu->bf16
//      5 Qt build: p=acc+bias+extra2[(gm&511)*512+gn]; q=extra[gm*512+gn];
//                  Qt[gm*1024 + (gn>>6)*128 + (gn&63)]      = (q+p)*0.125
//                  Qt[... + 64]                             =  q   *0.125
//      6 Kt build: m=acc+bias+extra2[...]; k=extra[...]; Kt=[k | m] (no scale)
//      7 Vt build: v=acc+bias+extra[gm*512+gn] (residual);
//                  Vt[((b*8+h)*64+d)*512 + s] = v   (b=gm>>9,s=gm&511,h=gn>>6,d=gn&63)
template<int EPI>
__global__ __launch_bounds__(256, 2) void gemm_kernel(
    const u16* __restrict__ A, const u16* __restrict__ WT,
    const float* __restrict__ bias, const float* __restrict__ extra,
    const float* __restrict__ extra2, void* __restrict__ outp,
    int M, int N, int K)
{
  __shared__ __align__(16) u16 As[128*32];   // unpadded: required by global_load_lds
  __shared__ __align__(16) u16 Bs[128*32];
  const int tid = threadIdx.x;
  const int wave = tid>>6, lane = tid&63, quad = lane>>4, l16 = lane&15;
  const int wm = wave>>1, wn = wave&1;
  const int m0 = blockIdx.y*128, n0 = blockIdx.x*128;

  f32x4 acc[4][4] = {};

  const int r1 = tid>>2, ch1 = (tid&3)*8;        // tid*16B -> rows 0..63
  const u16* pa0 = A  + (size_t)(m0+r1)*K + ch1;
  const u16* pa1 = pa0 + (size_t)64*K;
  const u16* pb0 = WT + (size_t)(n0+r1)*K + ch1;
  const u16* pb1 = pb0 + (size_t)64*K;
  u16* sa = &As[tid*8];                          // lane-contiguous dest
  u16* sb = &Bs[tid*8];

  for (int k0 = 0; k0 < K; k0 += 32) {
    gl16(pa0 + k0, sa);
    gl16(pa1 + k0, sa + 2048);                   // rows 64..127
    gl16(pb0 + k0, sb);
    gl16(pb1 + k0, sb + 2048);
    __syncthreads();                             // drains vmcnt (compiler-emitted)
    bf16x8 af[4], bf[4];
    #pragma unroll
    for (int i = 0; i < 4; ++i)
      af[i] = *(const bf16x8*)&As[(wm*64 + i*16 + l16)*32 + quad*8];
    #pragma unroll
    for (int j = 0; j < 4; ++j)
      bf[j] = *(const bf16x8*)&Bs[(wn*64 + j*16 + l16)*32 + quad*8];
    #pragma unroll
    for (int i = 0; i < 4; ++i)
      #pragma unroll
      for (int j = 0; j < 4; ++j)
        acc[i][j] = mfma16(af[i], bf[j], acc[i][j]);
    __syncthreads();
  }

  #pragma unroll
  for (int j = 0; j < 4; ++j) {
    int gn = n0 + wn*64 + j*16 + l16;
    float bv = bias[gn];
    #pragma unroll
    for (int i = 0; i < 4; ++i) {
      int gmb = m0 + wm*64 + i*16 + quad*4;
      #pragma unroll
      for (int r = 0; r < 4; ++r) {
        int gm = gmb + r;
        float v = acc[i][j][r] + bv;
        if (EPI == 0) {
          ((float*)outp)[(size_t)gm*N + gn] = v;
        } else if (EPI == 1) {
          ((float*)outp)[(size_t)gm*N + gn] = v*0.5f;
        } else if (EPI == 4) {
          v = 0.5f*v*(1.0f + erff(v*0.70710678118654752f));
          ((u16*)outp)[(size_t)gm*N + gn] = f2b(v);
        } else if (EPI == 5 || EPI == 6) {
          float p = v + extra2[(size_t)(gm & 511)*512 + gn];
          float q = extra[(size_t)gm*512 + gn];
          u16* o = (u16*)outp + (size_t)gm*1024 + ((gn>>6)*128) + (gn&63);
          if (EPI == 5) { o[0] = f2b((q + p)*0.125f); o[64] = f2b(q*0.125f); }
          else          { o[0] = f2b(q);              o[64] = f2b(p); }
        } else if (EPI == 7) {
          v += extra[(size_t)gm*512 + gn];
          int b = gm>>9, s = gm&511, h = gn>>6, d = gn&63;
          ((u16*)outp)[(size_t)((b*8 + h)*64 + d)*512 + s] = f2b(v);
        }
      }
    }
  }
}

// ---------------- flash attention v2 ----------------
// grid (qt2=4, h=8, b=32); 8 waves; 128 q-rows/block; 64-col k-tiles,
// double-buffered K/V LDS with register prefetch (1 barrier/iter).
// Qt/Kt token-major [B*S, 1024] (h*128 + [0..127]); Vt [B,8,64,S]; Qt holds
// 0.125 scale already. ctx out: [M,512] bf16.
__global__ __launch_bounds__(512, 4) void attn_kernel(
    const u16* __restrict__ Qt, const u16* __restrict__ Kt,
    const u16* __restrict__ Vt, const int* __restrict__ iseq,
    u16* __restrict__ ctx)
{
  const int qt2 = blockIdx.x, h = blockIdx.y, b = blockIdx.z;
  const int tid = threadIdx.x;
  const int wave = tid >> 6, lane = tid & 63, quad = lane >> 4, l16 = lane & 15;

  __shared__ __align__(16) u16 Ks[2][64*136];   // [s][128] +8 pad (2-way free)
  __shared__ __align__(16) u16 Vs[2][64*72];    // [d][64 s] +8 pad
  __shared__ __align__(16) u16 Ps[8][16*72];    // per-wave P
  __shared__ u16 validS[512];

  const int q0 = qt2 * 128;
  const int ntiles = 2*qt2 + 2;
  const u16* Qg = Qt + (size_t)(b*512)*1024 + h*128;
  const u16* Kg = Kt + (size_t)(b*512)*1024 + h*128;
  const u16* Vg = Vt + (size_t)((b*8 + h)*64)*512;

  if (tid < 512) validS[tid] = (u16)(iseq[b*512 + tid] > 0);

  // Q fragments in registers (A-operand layout): rows q0+wave*16+l16
  bf16x8 aq[4];
  {
    const size_t qr = (size_t)(q0 + wave*16 + l16) * 1024;
    #pragma unroll
    for (int ks = 0; ks < 4; ++ks)
      aq[ks] = *(const bf16x8*)&Qg[qr + ks*32 + quad*8];
  }

  // staging: K tile 64x128 (2 uint4/thread), V tile 64x64 (1 uint4/thread)
  const int krow = tid >> 4, kch = (tid & 15) * 8;
  const int vrow = tid >> 3, vch = (tid & 7) * 8;
  uint4 kreg0, kreg1, vreg;
  {
    kreg0 = *(const uint4*)&Kg[(size_t)krow*1024 + kch];
    kreg1 = *(const uint4*)&Kg[(size_t)(krow + 32)*1024 + kch];
    vreg  = *(const uint4*)&Vg[(size_t)vrow*512 + vch];
  }

  f32x4 Ob[4] = {};
  float mrow[4] = {-1e30f, -1e30f, -1e30f, -1e30f};
  float lrow[4] = {0.f, 0.f, 0.f, 0.f};
  const int qrow_base = q0 + wave*16 + quad*4;
  const int w_hi = q0 + wave*16 + 15;
  u16* Pw = Ps[wave];
  int buf = 0;

  for (int kt = 0; kt < ntiles; ++kt) {
    const int k0 = kt * 64;
    *(uint4*)&Ks[buf][krow*136 + kch]        = kreg0;
    *(uint4*)&Ks[buf][(krow + 32)*136 + kch] = kreg1;
    *(uint4*)&Vs[buf][vrow*72 + vch]         = vreg;
    __syncthreads();
    if (kt + 1 < ntiles) {                     // prefetch next tile into regs
      const int kn = k0 + 64;
      kreg0 = *(const uint4*)&Kg[(size_t)(kn + krow)*1024 + kch];
      kreg1 = *(const uint4*)&Kg[(size_t)(kn + krow + 32)*1024 + kch];
      vreg  = *(const uint4*)&Vg[(size_t)vrow*512 + kn + vch];
    }
    if (k0 <= w_hi) {                          // wave-uniform causal skip
      // scores = Q(16x128) @ K(64x128)^T  (already /8 via Qt scale)
      f32x4 sc[4] = {};
      #pragma unroll
      for (int ks = 0; ks < 4; ++ks) {
        #pragma unroll
        for (int j = 0; j < 4; ++j) {
          bf16x8 bk = *(const bf16x8*)&Ks[buf][(j*16 + l16)*136 + ks*32 + quad*8];
          sc[j] = mfma16(aq[ks], bk, sc[j]);
        }
      }
      // mask
      #pragma unroll
      for (int j = 0; j < 4; ++j) {
        int col = k0 + j*16 + l16;
        bool okc = (validS[col] != 0);
        #pragma unroll
        for (int r = 0; r < 4; ++r)
          sc[j][r] = (okc && col <= qrow_base + r) ? sc[j][r] : sc[j][r] - 10000.0f;
      }
      // online softmax (row on 16 lanes sharing quad)
      float alpha[4], pj[4][4];
      #pragma unroll
      for (int r = 0; r < 4; ++r) {
        float mx = fmaxf(fmaxf(sc[0][r], sc[1][r]), fmaxf(sc[2][r], sc[3][r]));
        #pragma unroll
        for (int d2 = 1; d2 < 16; d2 <<= 1) mx = fmaxf(mx, __shfl_xor(mx, d2, 64));
        float mn = fmaxf(mrow[r], mx);
        alpha[r] = __expf(mrow[r] - mn);
        mrow[r] = mn;
        float s0 = 0.f;
        #pragma unroll
        for (int j = 0; j < 4; ++j) { float p = __expf(sc[j][r] - mn); pj[j][r] = p; s0 += p; }
        #pragma unroll
        for (int d2 = 1; d2 < 16; d2 <<= 1) s0 += __shfl_xor(s0, d2, 64);
        lrow[r] = lrow[r]*alpha[r] + s0;
      }
      #pragma unroll
      for (int c = 0; c < 4; ++c)
        #pragma unroll
        for (int r = 0; r < 4; ++r) Ob[c][r] *= alpha[r];
      // P: C-layout -> LDS -> A-layout (same-wave in-order LDS, no barrier)
      #pragma unroll
      for (int j = 0; j < 4; ++j)
        #pragma unroll
        for (int r = 0; r < 4; ++r)
          Pw[(quad*4 + r)*72 + j*16 + l16] = f2b(pj[j][r]);
      // O += P[16x64] @ V[64x64]
      #pragma unroll
      for (int c = 0; c < 4; ++c) {
        #pragma unroll
        for (int k2 = 0; k2 < 2; ++k2) {
          bf16x8 ap = *(const bf16x8*)&Pw[l16*72 + k2*32 + quad*8];
          bf16x8 bv = *(const bf16x8*)&Vs[buf][(c*16 + l16)*72 + k2*32 + quad*8];
          Ob[c] = mfma16(ap, bv, Ob[c]);
        }
      }
    }
    buf ^= 1;
  }

  #pragma unroll
  for (int r = 0; r < 4; ++r) {
    float inv = 1.0f / lrow[r];
    int grow = b*512 + qrow_base + r;
    #pragma unroll
    for (int c = 0; c < 4; ++c)
      ctx[(size_t)grow*512 + h*64 + c*16 + l16] = f2b(Ob[c][r] * inv);
  }
}

// ---------------- LayerNorm over H=512, one wave per row ----------------
// RESBF: residual dtype (0=f32, 1=bf16). of/ob may be null.
template<int RESBF>
__global__ __launch_bounds__(256) void ln_kernel(
    const float* __restrict__ a, const void* __restrict__ resv,
    const float* __restrict__ g, const float* __restrict__ be,
    float* __restrict__ of, u16* __restrict__ ob)
{
  const int wave = threadIdx.x >> 6, lane = threadIdx.x & 63;
  const int row = blockIdx.x*4 + wave;
  const float4* pa = (const float4*)(a + (size_t)row*512);
  float4 v0 = pa[lane], v1 = pa[lane+64];
  float r[8];
  if (RESBF) {
    const ushort4* pr = (const ushort4*)((const u16*)resv + (size_t)row*512);
    ushort4 u0 = pr[lane], u1 = pr[lane+64];
    r[0]=b2f(u0.x); r[1]=b2f(u0.y); r[2]=b2f(u0.z); r[3]=b2f(u0.w);
    r[4]=b2f(u1.x); r[5]=b2f(u1.y); r[6]=b2f(u1.z); r[7]=b2f(u1.w);
  } else {
    const float4* pr = (const float4*)((const float*)resv + (size_t)row*512);
    float4 r0 = pr[lane], r1 = pr[lane+64];
    r[0]=r0.x; r[1]=r0.y; r[2]=r0.z; r[3]=r0.w;
    r[4]=r1.x; r[5]=r1.y; r[6]=r1.z; r[7]=r1.w;
  }
  v0.x += r[0]; v0.y += r[1]; v0.z += r[2]; v0.w += r[3];
  v1.x += r[4]; v1.y += r[5]; v1.z += r[6]; v1.w += r[7];
  float s = v0.x+v0.y+v0.z+v0.w + v1.x+v1.y+v1.z+v1.w;
  float q = v0.x*v0.x+v0.y*v0.y+v0.z*v0.z+v0.w*v0.w
          + v1.x*v1.x+v1.y*v1.y+v1.z*v1.z+v1.w*v1.w;
  #pragma unroll
  for (int d = 1; d < 64; d <<= 1) { s += __shfl_xor(s, d, 64); q += __shfl_xor(q, d, 64); }
  float mean = s * (1.0f/512.0f);
  float var  = q * (1.0f/512.0f) - mean*mean;
  float rstd = rsqrtf(var + 1e-12f);
  float4 g0 = ((const float4*)g)[lane],  g1 = ((const float4*)g)[lane+64];
  float4 b0 = ((const float4*)be)[lane], b1 = ((const float4*)be)[lane+64];
  float4 o0, o1;
  o0.x = (v0.x-mean)*rstd*g0.x + b0.x;  o0.y = (v0.y-mean)*rstd*g0.y + b0.y;
  o0.z = (v0.z-mean)*rstd*g0.z + b0.z;  o0.w = (v0.w-mean)*rstd*g0.w + b0.w;
  o1.x = (v1.x-mean)*rstd*g1.x + b1.x;  o1.y = (v1.y-mean)*rstd*g1.y + b1.y;
  o1.z = (v1.z-mean)*rstd*g1.z + b1.z;  o1.w = (v1.w-mean)*rstd*g1.w + b1.w;
  if (of) {
    ((float4*)(of + (size_t)row*512))[lane]    = o0;
    ((float4*)(of + (size_t)row*512))[lane+64] = o1;
  }
  if (ob) {
    ((ushort4*)(ob + (size_t)row*512))[lane]    = make_ushort4(f2b(o0.x), f2b(o0.y), f2b(o0.z), f2b(o0.w));
    ((ushort4*)(ob + (size_t)row*512))[lane+64] = make_ushort4(f2b(o1.x), f2b(o1.y), f2b(o1.z), f2b(o1.w));
  }
}

// ============================================================================
extern "C" void kernel_launch(void* const* d_in, const int* in_sizes, int n_in,
                              void* d_out, int out_size, void* d_ws, size_t ws_size,
                              hipStream_t stream) {
  (void)in_sizes; (void)n_in; (void)out_size; (void)ws_size;
  const float* x    = (const float*)d_in[0];
  const float* vin  = (const float*)d_in[1];
  const float* beh  = (const float*)d_in[2];
  const float* pos  = (const float*)d_in[3];
  const float* bq   = (const float*)d_in[5];
  const float* bk   = (const float*)d_in[7];
  const float* bv   = (const float*)d_in[9];
  const float* bpk  = (const float*)d_in[11];
  const float* bpq  = (const float*)d_in[13];
  const float* bbk  = (const float*)d_in[15];
  const float* bbq  = (const float*)d_in[17];
  const float* bd   = (const float*)d_in[19];
  const float* ln_g = (const float*)d_in[20];
  const float* ln_b = (const float*)d_in[21];
  const float* b1   = (const float*)d_in[23];
  const float* b2   = (const float*)d_in[25];
  const float* ln2_g= (const float*)d_in[26];
  const float* ln2_b= (const float*)d_in[27];
  const int*   iseq = (const int*)d_in[28];
  float* out = (float*)d_out;
  char* ws = (char*)d_ws;

  // ---- workspace (~178 MB) ----
  size_t off = 0;
  auto nxt = [&](size_t sz) { size_t r = off; off += (sz + 255) & ~(size_t)255; return r; };
  size_t oWT[8]; for (int i = 0; i < 8; ++i) oWT[i] = nxt(512*512*2);
  size_t oW1T = nxt((size_t)512*2048*2);
  size_t oW2T = nxt((size_t)512*2048*2);
  size_t oBk5 = nxt(512*4);
  size_t oBq5 = nxt(512*4);
  size_t oPb  = nxt(512*512*2);
  size_t oPK  = nxt(512*512*4);
  size_t oPQ  = nxt(512*512*4);
  size_t oXb  = nxt((size_t)NM*512*2);    // xb; dead after k-GEMM -> attn_out bf16 (ab)
  size_t oVb  = nxt((size_t)NM*512*2);    // vb; dead after v-GEMM -> ctx bf16 (Cb)
  size_t oBb  = nxt((size_t)NM*512*2);    // bb; dead after m-GEMM -> Vt
  size_t oR0  = nxt((size_t)NM*512*4);    // q/k raw f32, attn-proj raw, FFN2 raw
  size_t oQt  = nxt((size_t)NM*1024*2);   // Qt; Qt+Kt dead after attn -> h1 (67MB)
  size_t oKt  = nxt((size_t)NM*1024*2);   // contiguous with oQt

  u16* WT[8]; for (int i = 0; i < 8; ++i) WT[i] = (u16*)(ws + oWT[i]);
  u16*   W1T  = (u16*)(ws + oW1T);
  u16*   W2T  = (u16*)(ws + oW2T);
  float* Bbk5 = (float*)(ws + oBk5);
  float* Bbq5 = (float*)(ws + oBq5);
  u16*   posb = (u16*)(ws + oPb);
  float* PKh  = (float*)(ws + oPK);
  float* PQh  = (float*)(ws + oPQ);
  u16*   xb   = (u16*)(ws + oXb);
  u16*   vb   = (u16*)(ws + oVb);
  u16*   bb   = (u16*)(ws + oBb);
  float* R0   = (float*)(ws + oR0);
  u16*   Qtb  = (u16*)(ws + oQt);
  u16*   Ktb  = (u16*)(ws + oKt);
  u16*   Vtb  = (u16*)(ws + oBb);   // alias: bb dead
  u16*   Cb   = (u16*)(ws + oVb);   // alias: vb dead
  u16*   ab   = (u16*)(ws + oXb);   // alias: xb dead
  u16*   h1b  = (u16*)(ws + oQt);   // alias: Qt+Kt dead after attention

  // ---- prep ----
  cast_kernel<<<8192, 256, 0, stream>>>(x,   xb, NM*512/4);
  cast_kernel<<<8192, 256, 0, stream>>>(vin, vb, NM*512/4);
  cast_kernel<<<8192, 256, 0, stream>>>(beh, bb, NM*512/4);
  cast_kernel<<<256,  256, 0, stream>>>(pos, posb, 512*512/4);
  W8Args wa;
  const int wi[8] = {4, 6, 8, 10, 12, 14, 16, 18};   // Wq Wk Wv Wpk Wpq Wbk Wbq Wd
  for (int i = 0; i < 8; ++i) {
    wa.w[i] = (const float*)d_in[wi[i]];
    wa.o[i] = WT[i];
    wa.sc[i] = (i == 5 || i == 6) ? 0.5f : 1.0f;     // Wbk, Wbq pre-scaled 0.5
  }
  wprep8_kernel<<<dim3(8, 8, 8), 256, 0, stream>>>(wa);
  wprep_kernel<<<dim3(32, 8), 256, 0, stream>>>((const float*)d_in[22], W1T, 512, 2048);
  wprep_kernel<<<dim3(8, 32), 256, 0, stream>>>((const float*)d_in[24], W2T, 2048, 512);
  bias05_kernel<<<2, 256, 0, stream>>>(bbk, bbq, Bbk5, Bbq5);

  // ---- position projections: 0.5*(pos@W + b) ----
  gemm_kernel<1><<<dim3(4, 4), 256, 0, stream>>>(posb, WT[4], bpq, nullptr, nullptr, PQh, 512, 512, 512);
  gemm_kernel<1><<<dim3(4, 4), 256, 0, stream>>>(posb, WT[3], bpk, nullptr, nullptr, PKh, 512, 512, 512);

  // ---- Qt = [ (q+p)/8 | q/8 ],  Kt = [ k | m ]  (fused epilogue builds) ----
  gemm_kernel<0><<<dim3(4, 128), 256, 0, stream>>>(xb, WT[0], bq, nullptr, nullptr, R0, NM, 512, 512);
  gemm_kernel<5><<<dim3(4, 128), 256, 0, stream>>>(bb, WT[6], Bbq5, R0, PQh, Qtb, NM, 512, 512);
  gemm_kernel<0><<<dim3(4, 128), 256, 0, stream>>>(xb, WT[1], bk, nullptr, nullptr, R0, NM, 512, 512);
  gemm_kernel<6><<<dim3(4, 128), 256, 0, stream>>>(bb, WT[5], Bbk5, R0, PKh, Ktb, NM, 512, 512);

  // ---- V (+residual) -> transposed head layout (fused) ----
  gemm_kernel<7><<<dim3(4, 128), 256, 0, stream>>>(vb, WT[2], bv, vin, nullptr, Vtb, NM, 512, 512);

  // ---- attention ----
  attn_kernel<<<dim3(4, 8, 32), 512, 0, stream>>>(Qtb, Ktb, Vtb, iseq, Cb);

  // ---- output projection + LN1 (residual x, f32) -> bf16 ----
  gemm_kernel<0><<<dim3(4, 128), 256, 0, stream>>>(Cb, WT[7], bd, nullptr, nullptr, R0, NM, 512, 512);
  ln_kernel<0><<<4096, 256, 0, stream>>>(R0, x, ln_g, ln_b, nullptr, ab);

  // ---- FFN + LN2 (residual attn_out bf16) ----
  gemm_kernel<4><<<dim3(16, 128), 256, 0, stream>>>(ab,  W1T, b1, nullptr, nullptr, h1b, NM, 2048, 512);
  gemm_kernel<0><<<dim3(4, 128),  256, 0, stream>>>(h1b, W2T, b2, nullptr, nullptr, R0,  NM, 512, 2048);
  ln_kernel<1><<<4096, 256, 0, stream>>>(R0, ab, ln2_g, ln2_b, out, nullptr);
}

// Round 3
// 529.291 us; speedup vs baseline: 1.3956x; 1.2465x over previous
//
#include <hip/hip_runtime.h>
#include <math.h>

// ============================================================================
// acsasrec_decode2 v3.
//  - GEMM core: BK=64, global_load_lds(16B), XOR-swizzled unpadded LDS
//    (row stride 64 u16 = 128 B would be 16-way bank conflicted; swizzle
//    chunk c' = c ^ (row&7) makes frag b128 reads 2-way = free).
//  - QPKM fused dual-phase GEMM: Qt=[ (q+p)/8 | q/8 ] (continue-acc),
//    Kt=[ k | m ] (reset-acc), one dispatch, z in {0,1}.
//  - Attention: 512-thread blocks, 2 q-strips/wave (256 rows/block),
//    no-max softmax (masked weight = exp(s)*1e-30 — matches reference
//    fully-masked-row semantics), deferred l-reduction, dbuf K/V prefetch.
//  - 11 dispatches total.
// ============================================================================

typedef unsigned short u16;
typedef __attribute__((ext_vector_type(8))) short bf16x8;
typedef __attribute__((ext_vector_type(4))) float f32x4;

#define NM 16384        // B*S tokens

__device__ __forceinline__ u16 f2b(float f) {
  union { float f; unsigned u; } x; x.f = f;
  return (u16)((x.u + 0x7fffu + ((x.u >> 16) & 1u)) >> 16);  // RNE
}
__device__ __forceinline__ float b2f(u16 u) {
  union { unsigned u; float f; } x; x.u = ((unsigned)u) << 16; return x.f;
}
__device__ __forceinline__ f32x4 mfma16(bf16x8 a, bf16x8 b, f32x4 c) {
  return __builtin_amdgcn_mfma_f32_16x16x32_bf16(a, b, c, 0, 0, 0);
}
// async global->LDS, 16B/lane; LDS dest = wave-uniform base + lane*16.
__device__ __forceinline__ void gl16(const u16* g, u16* l) {
  __builtin_amdgcn_global_load_lds(
      (const __attribute__((address_space(1))) unsigned int*)(const void*)g,
      (__attribute__((address_space(3))) unsigned int*)(void*)l, 16, 0, 0);
}

// ---------------- shared BK=64 K-loop (swizzled LDS) ----------------
// A tile rows m0..m0+127 (lda), B tile rows n0..n0+127 (ldb). acc += A@B^T.
// pa/pb: per-thread gl16 source at k=0 (row tid>>3, swizzled chunk).
// sa/sb: per-thread LDS dest (= As/Bs + tid*8).
__device__ __forceinline__ void gemm_kloop(
    const u16* pa, const u16* pb, size_t lda, size_t ldb, int kiters,
    const u16* As, const u16* Bs, u16* sa, u16* sb, f32x4 (&acc)[4][4])
{
  const int tid = threadIdx.x;
  const int wave = tid>>6, lane = tid&63, quad = lane>>4, l16 = lane&15;
  const int wm = wave>>1, wn = wave&1;
  const int sw = l16 & 7;
  for (int it = 0; it < kiters; ++it) {
    const u16* pak = pa + it*64;
    const u16* pbk = pb + it*64;
    gl16(pak,          sa);
    gl16(pak + 32*lda, sa + 2048);
    gl16(pak + 64*lda, sa + 4096);
    gl16(pak + 96*lda, sa + 6144);
    gl16(pbk,          sb);
    gl16(pbk + 32*ldb, sb + 2048);
    gl16(pbk + 64*ldb, sb + 4096);
    gl16(pbk + 96*ldb, sb + 6144);
    __syncthreads();
    #pragma unroll
    for (int ks = 0; ks < 2; ++ks) {
      bf16x8 af[4], bf[4];
      #pragma unroll
      for (int i = 0; i < 4; ++i)
        af[i] = *(const bf16x8*)&As[(wm*64 + i*16 + l16)*64 + (((ks*4+quad)^sw)*8)];
      #pragma unroll
      for (int j = 0; j < 4; ++j)
        bf[j] = *(const bf16x8*)&Bs[(wn*64 + j*16 + l16)*64 + (((ks*4+quad)^sw)*8)];
      #pragma unroll
      for (int i = 0; i < 4; ++i)
        #pragma unroll
        for (int j = 0; j < 4; ++j)
          acc[i][j] = mfma16(af[i], bf[j], acc[i][j]);
    }
    __syncthreads();
  }
}

// per-thread staging source offset for a matrix with leading dim ld:
// row = base + (tid>>3), chunk = (tid&7) ^ ((tid>>3)&7)
__device__ __forceinline__ const u16* stage_src(const u16* M, int r0, size_t ld) {
  const int tid = threadIdx.x;
  return M + (size_t)(r0 + (tid>>3))*ld + (size_t)(((tid&7) ^ ((tid>>3)&7))*8);
}

// ---------------- cast f32 -> bf16 (all inputs, one dispatch) ----------------
__global__ __launch_bounds__(256) void cast_all_kernel(
    const float* __restrict__ x, const float* __restrict__ v,
    const float* __restrict__ be, const float* __restrict__ pos,
    u16* __restrict__ xb, u16* __restrict__ vb, u16* __restrict__ bb,
    u16* __restrict__ posb)
{
  int z = blockIdx.y;
  const float* in = (z==0) ? x : (z==1) ? v : (z==2) ? be : pos;
  u16* out = (z==0) ? xb : (z==1) ? vb : (z==2) ? bb : posb;
  int n4 = (z < 3) ? (NM*512/4) : (512*512/4);
  int i = blockIdx.x*256 + threadIdx.x;
  if (i >= n4) return;
  float4 w = ((const float4*)in)[i];
  ((ushort4*)out)[i] = make_ushort4(f2b(w.x), f2b(w.y), f2b(w.z), f2b(w.w));
}

// ---------------- weight prep: transpose+cast all 10 weights + biases -------
struct PrepArgs {
  const float* w[10];  // Wq Wk Wv Wpk Wpq Wbk Wbq Wd W1 W2
  u16* o[10];
  const float* bq; const float* bbq; const float* bbk;
  float* Bq2; float* Bk2;
};
__global__ __launch_bounds__(256) void wprep_all_kernel(PrepArgs a) {
  int job = blockIdx.x;
  if (job == 1024) {   // combined biases: Bq2 = bq + 0.5*bbq ; Bk2 = 0.5*bbk
    for (int i = threadIdx.x; i < 512; i += 256) {
      a.Bq2[i] = a.bq[i] + 0.5f*a.bbq[i];
      a.Bk2[i] = 0.5f*a.bbk[i];
    }
    return;
  }
  int wsel, n0, k0, K, N;
  if (job < 512)      { wsel = job>>6; int t = job&63;  n0=(t&7)*64;  k0=(t>>3)*64; K=512;  N=512; }
  else if (job < 768) { wsel = 8;      int t = job-512; n0=(t&31)*64; k0=(t>>5)*64; K=512;  N=2048; }
  else                { wsel = 9;      int t = job-768; n0=(t&7)*64;  k0=(t>>3)*64; K=2048; N=512; }
  float sc = (wsel == 5 || wsel == 6) ? 0.5f : 1.0f;    // Wbk, Wbq pre-scaled
  const float* in = a.w[wsel];
  u16* out = a.o[wsel];
  __shared__ __align__(16) u16 til[64*72];
  for (int idx = threadIdx.x; idx < 4096; idx += 256) {
    int r = idx>>6, c = idx&63;
    til[r*72+c] = f2b(in[(size_t)(k0+r)*N + n0+c] * sc);
  }
  __syncthreads();
  for (int idx = threadIdx.x; idx < 4096; idx += 256) {
    int r = idx>>6, c = idx&63;
    out[(size_t)(n0+r)*K + k0+c] = til[c*72+r];
  }
}

// ---------------- position projections: PQh/PKh = 0.5*(pos@W + b) -----------
__global__ __launch_bounds__(256, 3) void gemm_pos_kernel(
    const u16* __restrict__ posb, const u16* __restrict__ WTpq,
    const u16* __restrict__ WTpk, const float* __restrict__ bpq,
    const float* __restrict__ bpk, float* __restrict__ PQh,
    float* __restrict__ PKh)
{
  __shared__ __align__(16) u16 As[128*64];
  __shared__ __align__(16) u16 Bs[128*64];
  const int z = blockIdx.z;
  const u16* W = z ? WTpk : WTpq;
  const float* bias = z ? bpk : bpq;
  float* out = z ? PKh : PQh;
  const int tid = threadIdx.x;
  const int wave = tid>>6, lane = tid&63, quad = lane>>4, l16 = lane&15;
  const int wm = wave>>1, wn = wave&1;
  const int m0 = blockIdx.y*128, n0 = blockIdx.x*128;
  f32x4 acc[4][4] = {};
  gemm_kloop(stage_src(posb + (size_t)m0*512, 0, 512), stage_src(W + (size_t)n0*512, 0, 512),
             512, 512, 8, As, Bs, &As[tid*8], &Bs[tid*8], acc);
  #pragma unroll
  for (int j = 0; j < 4; ++j) {
    int gn = n0 + wn*64 + j*16 + l16;
    float bv = bias[gn];
    #pragma unroll
    for (int i = 0; i < 4; ++i) {
      int gm = m0 + wm*64 + i*16 + quad*4;
      #pragma unroll
      for (int r = 0; r < 4; ++r)
        out[(size_t)(gm+r)*512 + gn] = (acc[i][j][r] + bv)*0.5f;
    }
  }
}

// ---------------- QPKM fused dual-phase GEMM ----------------
// z=0: Qt. phase1 acc=x@Wq, mid-store (acc+bq)/8 at half +64; phase2 acc+=bb@.5Wbq;
//          final (acc+Bq2+PQh)/8 at half +0.   (Qt = [(q+p)/8 | q/8])
// z=1: Kt. phase1 acc=x@Wk, mid-store (acc+bk) at half +0; acc=0; phase2 bb@.5Wbk;
//          final (acc+Bk2+PKh) at half +64.    (Kt = [k | m])
__global__ __launch_bounds__(256, 3) void gemm_qk_kernel(
    const u16* __restrict__ xb, const u16* __restrict__ bb,
    const u16* __restrict__ WTq, const u16* __restrict__ WTk,
    const u16* __restrict__ WTbq, const u16* __restrict__ WTbk,
    const float* __restrict__ bq, const float* __restrict__ bk,
    const float* __restrict__ Bq2, const float* __restrict__ Bk2,
    const float* __restrict__ PQh, const float* __restrict__ PKh,
    u16* __restrict__ Qt, u16* __restrict__ Kt)
{
  __shared__ __align__(16) u16 As[128*64];
  __shared__ __align__(16) u16 Bs[128*64];
  const int z = blockIdx.z;
  const u16* W1 = z ? WTk : WTq;
  const u16* W2 = z ? WTbk : WTbq;
  const float* b1 = z ? bk : bq;
  const float* b2 = z ? Bk2 : Bq2;
  const float* ex = z ? PKh : PQh;
  u16* out = z ? Kt : Qt;
  const float scl = z ? 1.0f : 0.125f;
  const int tid = threadIdx.x;
  const int wave = tid>>6, lane = tid&63, quad = lane>>4, l16 = lane&15;
  const int wm = wave>>1, wn = wave&1;
  const int m0 = blockIdx.y*128, n0 = blockIdx.x*128;
  u16* sa = &As[tid*8];  u16* sb = &Bs[tid*8];

  f32x4 acc[4][4] = {};
  gemm_kloop(stage_src(xb + (size_t)m0*512, 0, 512), stage_src(W1 + (size_t)n0*512, 0, 512),
             512, 512, 8, As, Bs, sa, sb, acc);
  // mid-epilogue: store phase-1 half
  {
    const int hoff = z ? 0 : 64;
    #pragma unroll
    for (int j = 0; j < 4; ++j) {
      int gn = n0 + wn*64 + j*16 + l16;
      float bv = b1[gn];
      size_t col = (size_t)((gn>>6)*128 + (gn&63) + hoff);
      #pragma unroll
      for (int i = 0; i < 4; ++i) {
        int gm = m0 + wm*64 + i*16 + quad*4;
        #pragma unroll
        for (int r = 0; r < 4; ++r)
          out[(size_t)(gm+r)*1024 + col] = f2b((acc[i][j][r] + bv)*scl);
      }
    }
  }
  if (z) {
    #pragma unroll
    for (int i = 0; i < 4; ++i)
      #pragma unroll
      for (int j = 0; j < 4; ++j)
        acc[i][j] = f32x4{0.f, 0.f, 0.f, 0.f};
  }
  gemm_kloop(stage_src(bb + (size_t)m0*512, 0, 512), stage_src(W2 + (size_t)n0*512, 0, 512),
             512, 512, 8, As, Bs, sa, sb, acc);
  // final epilogue: store phase-2 half
  {
    const int hoff = z ? 64 : 0;
    #pragma unroll
    for (int j = 0; j < 4; ++j) {
      int gn = n0 + wn*64 + j*16 + l16;
      float bv = b2[gn];
      size_t col = (size_t)((gn>>6)*128 + (gn&63) + hoff);
      #pragma unroll
      for (int i = 0; i < 4; ++i) {
        int gm = m0 + wm*64 + i*16 + quad*4;
        #pragma unroll
        for (int r = 0; r < 4; ++r)
          out[(size_t)(gm+r)*1024 + col] =
              f2b((acc[i][j][r] + bv + ex[(size_t)((gm+r)&511)*512 + gn])*scl);
      }
    }
  }
}

// ---------------- general GEMM with epilogues ----------------
// EPI 0: +bias -> f32         (FFN2)
// EPI 4: gelu(+bias) -> bf16  (FFN1)
// EPI 7: +bias + bf16 residual -> Vt scatter [B,8,64,S]  (V projection)
// EPI 8: +bias + bf16 residual -> f32  (attn output projection + x residual)
template<int EPI>
__global__ __launch_bounds__(256, 3) void gemm_epi_kernel(
    const u16* __restrict__ A, const u16* __restrict__ W,
    const float* __restrict__ bias, const void* __restrict__ extra,
    void* __restrict__ outp, int M, int N, int K)
{
  __shared__ __align__(16) u16 As[128*64];
  __shared__ __align__(16) u16 Bs[128*64];
  const int tid = threadIdx.x;
  const int wave = tid>>6, lane = tid&63, quad = lane>>4, l16 = lane&15;
  const int wm = wave>>1, wn = wave&1;
  const int m0 = blockIdx.y*128, n0 = blockIdx.x*128;
  f32x4 acc[4][4] = {};
  gemm_kloop(stage_src(A + (size_t)m0*K, 0, K), stage_src(W + (size_t)n0*K, 0, K),
             K, K, K>>6, As, Bs, &As[tid*8], &Bs[tid*8], acc);
  #pragma unroll
  for (int j = 0; j < 4; ++j) {
    int gn = n0 + wn*64 + j*16 + l16;
    float bv = bias[gn];
    #pragma unroll
    for (int i = 0; i < 4; ++i) {
      int gmb = m0 + wm*64 + i*16 + quad*4;
      #pragma unroll
      for (int r = 0; r < 4; ++r) {
        int gm = gmb + r;
        float v = acc[i][j][r] + bv;
        if (EPI == 0) {
          ((float*)outp)[(size_t)gm*N + gn] = v;
        } else if (EPI == 4) {
          v = 0.5f*v*(1.0f + erff(v*0.70710678118654752f));
          ((u16*)outp)[(size_t)gm*N + gn] = f2b(v);
        } else if (EPI == 7) {
          v += b2f(((const u16*)extra)[(size_t)gm*512 + gn]);
          int b = gm>>9, s = gm&511, h = gn>>6, d = gn&63;
          ((u16*)outp)[(size_t)((b*8 + h)*64 + d)*512 + s] = f2b(v);
        } else if (EPI == 8) {
          v += b2f(((const u16*)extra)[(size_t)gm*512 + gn]);
          ((float*)outp)[(size_t)gm*N + gn] = v;
        }
      }
    }
  }
}

// ---------------- flash attention v3 ----------------
// grid (qh=2, h=8, b=32); 512 threads (8 waves); 2 q-strips/wave = 256 rows/blk.
// No-max softmax: p = exp(s)*sel, sel in {1, 1e-30}; masked-row semantics match
// reference (softmax of uniform -10000-shifted scores). Qt pre-scaled /8.
__global__ __launch_bounds__(512, 2) void attn_kernel(
    const u16* __restrict__ Qt, const u16* __restrict__ Kt,
    const u16* __restrict__ Vt, const int* __restrict__ iseq,
    u16* __restrict__ ctx)
{
  const int qh = blockIdx.x, h = blockIdx.y, b = blockIdx.z;
  const int tid = threadIdx.x;
  const int wave = tid>>6, lane = tid&63, quad = lane>>4, l16 = lane&15;

  __shared__ __align__(16) u16 Ks[2][64*136];
  __shared__ __align__(16) u16 Vs[2][64*72];
  __shared__ __align__(16) u16 Ps[8][16*72];
  __shared__ float sel[512];

  const int q0 = qh*256;
  const int ntiles = 4*qh + 4;
  const u16* Qg = Qt + (size_t)(b*512)*1024 + h*128;
  const u16* Kg = Kt + (size_t)(b*512)*1024 + h*128;
  const u16* Vg = Vt + (size_t)((b*8 + h)*64)*512;

  if (tid < 512) sel[tid] = (iseq[b*512 + tid] > 0) ? 1.0f : 1e-30f;

  // Q fragments (A-layout), strips s=0,1: rows q0 + s*128 + wave*16 + l16
  bf16x8 aq[2][4];
  #pragma unroll
  for (int s = 0; s < 2; ++s) {
    const size_t qr = (size_t)(q0 + s*128 + wave*16 + l16)*1024;
    #pragma unroll
    for (int ks = 0; ks < 4; ++ks)
      aq[s][ks] = *(const bf16x8*)&Qg[qr + ks*32 + quad*8];
  }

  // staging (512 threads): K 64x128 = 2 uint4/thr, V 64x64 = 1 uint4/thr
  const int sr = tid>>3, sc8 = (tid&7)*8, sc16 = (tid&7)*16;
  uint4 kreg0 = *(const uint4*)&Kg[(size_t)sr*1024 + sc16];
  uint4 kreg1 = *(const uint4*)&Kg[(size_t)sr*1024 + sc16 + 8];
  uint4 vreg  = *(const uint4*)&Vg[(size_t)sr*512 + sc8];

  f32x4 Ob[2][4] = {};
  float lrow[2][4] = {};
  u16* Pw = Ps[wave];
  int buf = 0;

  for (int kt = 0; kt < ntiles; ++kt) {
    const int k0 = kt*64;
    *(uint4*)&Ks[buf][sr*136 + sc16]     = kreg0;
    *(uint4*)&Ks[buf][sr*136 + sc16 + 8] = kreg1;
    *(uint4*)&Vs[buf][sr*72 + sc8]       = vreg;
    __syncthreads();
    if (kt + 1 < ntiles) {
      const int kn = k0 + 64;
      kreg0 = *(const uint4*)&Kg[(size_t)(kn + sr)*1024 + sc16];
      kreg1 = *(const uint4*)&Kg[(size_t)(kn + sr)*1024 + sc16 + 8];
      vreg  = *(const uint4*)&Vg[(size_t)sr*512 + kn + sc8];
    }
    const bool act0 = (q0 + wave*16 + 15) >= k0;         // strip 0
    const bool act1 = (q0 + 128 + wave*16 + 15) >= k0;   // strip 1 (superset)
    if (act1) {
      f32x4 sc[2][4] = {};
      #pragma unroll
      for (int ks = 0; ks < 4; ++ks) {
        bf16x8 bk[4];
        #pragma unroll
        for (int j = 0; j < 4; ++j)
          bk[j] = *(const bf16x8*)&Ks[buf][(j*16 + l16)*136 + ks*32 + quad*8];
        if (act0) {
          #pragma unroll
          for (int j = 0; j < 4; ++j) sc[0][j] = mfma16(aq[0][ks], bk[j], sc[0][j]);
        }
        #pragma unroll
        for (int j = 0; j < 4; ++j) sc[1][j] = mfma16(aq[1][ks], bk[j], sc[1][j]);
      }
      #pragma unroll
      for (int s = 0; s < 2; ++s) {
        if (s == 0 && !act0) continue;
        const int rb = q0 + s*128 + wave*16 + quad*4;
        float pj[4][4];
        #pragma unroll
        for (int j = 0; j < 4; ++j) {
          int col = k0 + j*16 + l16;
          float fs = sel[col];
          #pragma unroll
          for (int r = 0; r < 4; ++r) {
            float m2 = (col <= rb + r) ? fs : 1e-30f;
            pj[j][r] = __expf(sc[s][j][r]) * m2;
          }
        }
        #pragma unroll
        for (int r = 0; r < 4; ++r)
          lrow[s][r] += pj[0][r] + pj[1][r] + pj[2][r] + pj[3][r];
        #pragma unroll
        for (int j = 0; j < 4; ++j)
          #pragma unroll
          for (int r = 0; r < 4; ++r)
            Pw[(quad*4 + r)*72 + j*16 + l16] = f2b(pj[j][r]);
        #pragma unroll
        for (int c = 0; c < 4; ++c) {
          #pragma unroll
          for (int k2 = 0; k2 < 2; ++k2) {
            bf16x8 ap = *(const bf16x8*)&Pw[l16*72 + k2*32 + quad*8];
            bf16x8 bv = *(const bf16x8*)&Vs[buf][(c*16 + l16)*72 + k2*32 + quad*8];
            Ob[s][c] = mfma16(ap, bv, Ob[s][c]);
          }
        }
      }
    }
    buf ^= 1;
  }

  #pragma unroll
  for (int s = 0; s < 2; ++s) {
    #pragma unroll
    for (int r = 0; r < 4; ++r) {
      float l = lrow[s][r];
      #pragma unroll
      for (int d2 = 1; d2 < 16; d2 <<= 1) l += __shfl_xor(l, d2, 64);
      float inv = 1.0f / l;
      int grow = b*512 + q0 + s*128 + wave*16 + quad*4 + r;
      #pragma unroll
      for (int c = 0; c < 4; ++c)
        ctx[(size_t)grow*512 + h*64 + c*16 + l16] = f2b(Ob[s][c][r]*inv);
    }
  }
}

// ---------------- LayerNorm over H=512, one wave per row ----------------
// RES: 0 = f32 residual, 1 = bf16 residual, 2 = none. of/ob may be null.
template<int RES>
__global__ __launch_bounds__(256) void ln_kernel(
    const float* __restrict__ a, const void* __restrict__ resv,
    const float* __restrict__ g, const float* __restrict__ be,
    float* __restrict__ of, u16* __restrict__ ob)
{
  const int wave = threadIdx.x >> 6, lane = threadIdx.x & 63;
  const int row = blockIdx.x*4 + wave;
  const float4* pa = (const float4*)(a + (size_t)row*512);
  float4 v0 = pa[lane], v1 = pa[lane+64];
  if (RES == 1) {
    const ushort4* pr = (const ushort4*)((const u16*)resv + (size_t)row*512);
    ushort4 u0 = pr[lane], u1 = pr[lane+64];
    v0.x += b2f(u0.x); v0.y += b2f(u0.y); v0.z += b2f(u0.z); v0.w += b2f(u0.w);
    v1.x += b2f(u1.x); v1.y += b2f(u1.y); v1.z += b2f(u1.z); v1.w += b2f(u1.w);
  } else if (RES == 0) {
    const float4* pr = (const float4*)((const float*)resv + (size_t)row*512);
    float4 r0 = pr[lane], r1 = pr[lane+64];
    v0.x += r0.x; v0.y += r0.y; v0.z += r0.z; v0.w += r0.w;
    v1.x += r1.x; v1.y += r1.y; v1.z += r1.z; v1.w += r1.w;
  }
  float s = v0.x+v0.y+v0.z+v0.w + v1.x+v1.y+v1.z+v1.w;
  float q = v0.x*v0.x+v0.y*v0.y+v0.z*v0.z+v0.w*v0.w
          + v1.x*v1.x+v1.y*v1.y+v1.z*v1.z+v1.w*v1.w;
  #pragma unroll
  for (int d = 1; d < 64; d <<= 1) { s += __shfl_xor(s, d, 64); q += __shfl_xor(q, d, 64); }
  float mean = s * (1.0f/512.0f);
  float var  = q * (1.0f/512.0f) - mean*mean;
  float rstd = rsqrtf(var + 1e-12f);
  float4 g0 = ((const float4*)g)[lane],  g1 = ((const float4*)g)[lane+64];
  float4 b0 = ((const float4*)be)[lane], b1 = ((const float4*)be)[lane+64];
  float4 o0, o1;
  o0.x = (v0.x-mean)*rstd*g0.x + b0.x;  o0.y = (v0.y-mean)*rstd*g0.y + b0.y;
  o0.z = (v0.z-mean)*rstd*g0.z + b0.z;  o0.w = (v0.w-mean)*rstd*g0.w + b0.w;
  o1.x = (v1.x-mean)*rstd*g1.x + b1.x;  o1.y = (v1.y-mean)*rstd*g1.y + b1.y;
  o1.z = (v1.z-mean)*rstd*g1.z + b1.z;  o1.w = (v1.w-mean)*rstd*g1.w + b1.w;
  if (of) {
    ((float4*)(of + (size_t)row*512))[lane]    = o0;
    ((float4*)(of + (size_t)row*512))[lane+64] = o1;
  }
  if (ob) {
    ((ushort4*)(ob + (size_t)row*512))[lane]    = make_ushort4(f2b(o0.x), f2b(o0.y), f2b(o0.z), f2b(o0.w));
    ((ushort4*)(ob + (size_t)row*512))[lane+64] = make_ushort4(f2b(o1.x), f2b(o1.y), f2b(o1.z), f2b(o1.w));
  }
}

// ============================================================================
extern "C" void kernel_launch(void* const* d_in, const int* in_sizes, int n_in,
                              void* d_out, int out_size, void* d_ws, size_t ws_size,
                              hipStream_t stream) {
  (void)in_sizes; (void)n_in; (void)out_size; (void)ws_size;
  const float* x    = (const float*)d_in[0];
  const float* vin  = (const float*)d_in[1];
  const float* beh  = (const float*)d_in[2];
  const float* pos  = (const float*)d_in[3];
  const float* bq   = (const float*)d_in[5];
  const float* bk   = (const float*)d_in[7];
  const float* bv   = (const float*)d_in[9];
  const float* bpk  = (const float*)d_in[11];
  const float* bpq  = (const float*)d_in[13];
  const float* bbk  = (const float*)d_in[15];
  const float* bbq  = (const float*)d_in[17];
  const float* bd   = (const float*)d_in[19];
  const float* ln_g = (const float*)d_in[20];
  const float* ln_b = (const float*)d_in[21];
  const float* b1   = (const float*)d_in[23];
  const float* b2   = (const float*)d_in[25];
  const float* ln2_g= (const float*)d_in[26];
  const float* ln2_b= (const float*)d_in[27];
  const int*   iseq = (const int*)d_in[28];
  float* out = (float*)d_out;
  char* ws = (char*)d_ws;

  // ---- workspace (~195 MB) ----
  size_t off = 0;
  auto nxt = [&](size_t sz) { size_t r = off; off += (sz + 255) & ~(size_t)255; return r; };
  size_t oWT[8]; for (int i = 0; i < 8; ++i) oWT[i] = nxt(512*512*2);
  size_t oW1T = nxt((size_t)512*2048*2);
  size_t oW2T = nxt((size_t)512*2048*2);
  size_t oBq2 = nxt(512*4);
  size_t oBk2 = nxt(512*4);
  size_t oPb  = nxt(512*512*2);
  size_t oPK  = nxt(512*512*4);
  size_t oPQ  = nxt(512*512*4);
  size_t oXb  = nxt((size_t)NM*512*2);    // xb; dead after d-gemm -> ab
  size_t oVb  = nxt((size_t)NM*512*2);    // vb; dead after V-gemm -> Cb
  size_t oBb  = nxt((size_t)NM*512*2);    // bb; dead after gemm_qk -> Vt
  size_t oR0  = nxt((size_t)NM*512*4);    // f32 scratch (d-out, FFN2-out)
  size_t oQt  = nxt((size_t)NM*1024*2);   // Qt; Qt+Kt dead after attn -> h1b
  size_t oKt  = nxt((size_t)NM*1024*2);   // contiguous with oQt

  u16* WT[8]; for (int i = 0; i < 8; ++i) WT[i] = (u16*)(ws + oWT[i]);
  u16*   W1T  = (u16*)(ws + oW1T);
  u16*   W2T  = (u16*)(ws + oW2T);
  float* Bq2  = (float*)(ws + oBq2);
  float* Bk2  = (float*)(ws + oBk2);
  u16*   posb = (u16*)(ws + oPb);
  float* PKh  = (float*)(ws + oPK);
  float* PQh  = (float*)(ws + oPQ);
  u16*   xb   = (u16*)(ws + oXb);
  u16*   vb   = (u16*)(ws + oVb);
  u16*   bb   = (u16*)(ws + oBb);
  float* R0   = (float*)(ws + oR0);
  u16*   Qtb  = (u16*)(ws + oQt);
  u16*   Ktb  = (u16*)(ws + oKt);
  u16*   Vtb  = (u16*)(ws + oBb);   // alias: bb dead after gemm_qk
  u16*   Cb   = (u16*)(ws + oVb);   // alias: vb dead after V-gemm
  u16*   ab   = (u16*)(ws + oXb);   // alias: xb dead after d-gemm
  u16*   h1b  = (u16*)(ws + oQt);   // alias: Qt+Kt dead after attn

  // 1. casts
  cast_all_kernel<<<dim3(8192, 4), 256, 0, stream>>>(x, vin, beh, pos, xb, vb, bb, posb);
  // 2. weight prep (+ combined biases)
  PrepArgs pa;
  const int wi[10] = {4, 6, 8, 10, 12, 14, 16, 18, 22, 24};
  for (int i = 0; i < 10; ++i) pa.w[i] = (const float*)d_in[wi[i]];
  for (int i = 0; i < 8; ++i)  pa.o[i] = WT[i];
  pa.o[8] = W1T; pa.o[9] = W2T;
  pa.bq = bq; pa.bbq = bbq; pa.bbk = bbk; pa.Bq2 = Bq2; pa.Bk2 = Bk2;
  wprep_all_kernel<<<1025, 256, 0, stream>>>(pa);
  // 3. position projections
  gemm_pos_kernel<<<dim3(4, 4, 2), 256, 0, stream>>>(posb, WT[4], WT[3], bpq, bpk, PQh, PKh);
  // 4. Qt & Kt (fused dual-phase)
  gemm_qk_kernel<<<dim3(4, 128, 2), 256, 0, stream>>>(
      xb, bb, WT[0], WT[1], WT[6], WT[5], bq, bk, Bq2, Bk2, PQh, PKh, Qtb, Ktb);
  // 5. V projection (+bf16 residual) -> Vt
  gemm_epi_kernel<7><<<dim3(4, 128), 256, 0, stream>>>(vb, WT[2], bv, vb, Vtb, NM, 512, 512);
  // 6. attention
  attn_kernel<<<dim3(2, 8, 32), 512, 0, stream>>>(Qtb, Ktb, Vtb, iseq, Cb);
  // 7. output projection + x residual (bf16)
  gemm_epi_kernel<8><<<dim3(4, 128), 256, 0, stream>>>(Cb, WT[7], bd, xb, R0, NM, 512, 512);
  // 8. LN1 -> bf16
  ln_kernel<2><<<4096, 256, 0, stream>>>(R0, nullptr, ln_g, ln_b, nullptr, ab);
  // 9. FFN1 (gelu) -> bf16
  gemm_epi_kernel<4><<<dim3(16, 128), 256, 0, stream>>>(ab, W1T, b1, nullptr, h1b, NM, 2048, 512);
  // 10. FFN2 -> f32
  gemm_epi_kernel<0><<<dim3(4, 128), 256, 0, stream>>>(h1b, W2T, b2, nullptr, R0, NM, 512, 2048);
  // 11. LN2 (+bf16 residual) -> out
  ln_kernel<1><<<4096, 256, 0, stream>>>(R0, ab, ln2_g, ln2_b, out, nullptr);
}

// Round 5
// 515.812 us; speedup vs baseline: 1.4321x; 1.0261x over previous
//
#include <hip/hip_runtime.h>
#include <math.h>

// ============================================================================
// acsasrec_decode2 v4.1 (v4 + comment-backslash compile fix).
//  - score = (q+p)·k + q·m  => no Qt/Kt intermediates; attention combines
//    q+p in-register, stages K-LDS as [k|m] from Kraw/Mraw.
//  - One 2560-block projection dispatch (q,k,p,m,v), BK=32 kloop (round-2,
//    empirically fastest), LDS-staged vectorized bf16 epilogues.
//  - V epilogue writes transposed Vt via LDS tile; value-residual harvested
//    from the staged A-tile in LDS during matching k-iters (free).
//  - 10 dispatches.
// ============================================================================

typedef unsigned short u16;
typedef __attribute__((ext_vector_type(8))) short bf16x8;
typedef __attribute__((ext_vector_type(4))) float f32x4;

#define NM 16384        // B*S tokens

__device__ __forceinline__ u16 f2b(float f) {
  union { float f; unsigned u; } x; x.f = f;
  return (u16)((x.u + 0x7fffu + ((x.u >> 16) & 1u)) >> 16);  // RNE
}
__device__ __forceinline__ float b2f(u16 u) {
  union { unsigned u; float f; } x; x.u = ((unsigned)u) << 16; return x.f;
}
__device__ __forceinline__ f32x4 mfma16(bf16x8 a, bf16x8 b, f32x4 c) {
  return __builtin_amdgcn_mfma_f32_16x16x32_bf16(a, b, c, 0, 0, 0);
}
// async global->LDS, 16B/lane; LDS dest = wave-uniform base + lane*16.
__device__ __forceinline__ void gl16(const u16* g, u16* l) {
  __builtin_amdgcn_global_load_lds(
      (const __attribute__((address_space(1))) unsigned int*)(const void*)g,
      (__attribute__((address_space(3))) unsigned int*)(void*)l, 16, 0, 0);
}
__device__ __forceinline__ bf16x8 baddv(bf16x8 a, bf16x8 b) {
  bf16x8 r;
  #pragma unroll
  for (int e = 0; e < 8; ++e) r[e] = (short)f2b(b2f((u16)a[e]) + b2f((u16)b[e]));
  return r;
}

// ---------------- BK=32 K-loop (round-2 structure, proven fastest) ----------
// If vres: acc[i][j] += A-element at (row, col=gn) harvested from staged LDS
// tile when the k-window covers this block's output columns (value residual).
__device__ __forceinline__ void kloop(
    const u16* __restrict__ A, const u16* __restrict__ W,
    int m0, int n0, int K, int kiters, u16* As, u16* Bs, bool vres,
    f32x4 (&acc)[4][4])
{
  const int tid = threadIdx.x;
  const int wave = tid>>6, lane = tid&63, quad = lane>>4, l16 = lane&15;
  const int wm = wave>>1, wn = wave&1;
  const int r1 = tid>>2, ch1 = (tid&3)*8;
  const u16* pA = A + (size_t)(m0+r1)*K + ch1;
  const u16* pB = W + (size_t)(n0+r1)*K + ch1;
  u16* sa = As + tid*8;  u16* sb = Bs + tid*8;
  for (int it = 0; it < kiters; ++it) {
    const int k0 = it*32;
    gl16(pA + k0, sa); gl16(pA + (size_t)64*K + k0, sa + 2048);
    gl16(pB + k0, sb); gl16(pB + (size_t)64*K + k0, sb + 2048);
    __syncthreads();
    bf16x8 af[4], bf[4];
    #pragma unroll
    for (int i = 0; i < 4; ++i)
      af[i] = *(const bf16x8*)&As[(wm*64 + i*16 + l16)*32 + quad*8];
    #pragma unroll
    for (int j = 0; j < 4; ++j)
      bf[j] = *(const bf16x8*)&Bs[(wn*64 + j*16 + l16)*32 + quad*8];
    if (vres) {     // value residual from staged A-tile (N==K==512 space)
      #pragma unroll
      for (int j = 0; j < 4; ++j) {
        const int start = n0 + wn*64 + j*16;
        if ((start & ~31) == k0) {
          const int c = (start & 31) + l16;
          #pragma unroll
          for (int i = 0; i < 4; ++i)
            #pragma unroll
            for (int rr = 0; rr < 4; ++rr)
              acc[i][j][rr] += b2f(As[(wm*64 + i*16 + quad*4 + rr)*32 + c]);
        }
      }
    }
    #pragma unroll
    for (int i = 0; i < 4; ++i)
      #pragma unroll
      for (int j = 0; j < 4; ++j)
        acc[i][j] = mfma16(af[i], bf[j], acc[i][j]);
    __syncthreads();
  }
}

// ---------------- standard epilogue: acc -> LDS bf16 tile -> 16B stores -----
// out[M,N] bf16; v = (acc + bias [gelu]) [+ex] * scale.
// exmode: 0 none | 1 ex[(gr%512)*512+gc] | 2 ex[gr*512+gc]  (ex is bf16)
__device__ __forceinline__ void epi_std(
    f32x4 (&acc)[4][4], const float* __restrict__ bias,
    const u16* __restrict__ ex, int exmode, float scale, int gelu,
    u16* __restrict__ out, int m0, int n0, int N, u16* til)
{
  const int tid = threadIdx.x;
  const int wave = tid>>6, lane = tid&63, quad = lane>>4, l16 = lane&15;
  const int wm = wave>>1, wn = wave&1;
  #pragma unroll
  for (int pass = 0; pass < 2; ++pass) {
    if (wm == pass) {
      #pragma unroll
      for (int j = 0; j < 4; ++j) {
        const int c = wn*64 + j*16 + l16;
        const float bv = bias[n0 + c];
        #pragma unroll
        for (int i = 0; i < 4; ++i)
          #pragma unroll
          for (int rr = 0; rr < 4; ++rr) {
            float v = acc[i][j][rr] + bv;
            if (gelu) v = 0.5f*v*(1.0f + erff(v*0.70710678118654752f));
            til[(i*16 + quad*4 + rr)*136 + c] = f2b(v);
          }
      }
    }
    __syncthreads();
    const int r = tid>>2, ck = tid&3;
    const int gr = m0 + pass*64 + r;
    #pragma unroll
    for (int kk = 0; kk < 4; ++kk) {
      const int cc = ck*32 + kk*8, gc = n0 + cc;
      u16 e8[8];
      *(uint4*)e8 = *(const uint4*)&til[r*136 + cc];
      if (exmode) {
        const u16* ep = (exmode == 1) ? &ex[(size_t)(gr & 511)*512 + gc]
                                      : &ex[(size_t)gr*512 + gc];
        #pragma unroll
        for (int e = 0; e < 8; ++e) e8[e] = f2b((b2f(e8[e]) + b2f(ep[e]))*scale);
      } else if (scale != 1.0f) {
        #pragma unroll
        for (int e = 0; e < 8; ++e) e8[e] = f2b(b2f(e8[e])*scale);
      }
      *(uint4*)&out[(size_t)gr*N + gc] = *(uint4*)e8;
    }
    __syncthreads();
  }
}

// ---------------- V epilogue: transposed store -> Vt[B*8*64, 512] ----------
__device__ __forceinline__ void epi_vt(
    f32x4 (&acc)[4][4], const float* __restrict__ bias,
    u16* __restrict__ Vt, int m0, int n0, u16* til)
{
  const int tid = threadIdx.x;
  const int wave = tid>>6, lane = tid&63, quad = lane>>4, l16 = lane&15;
  const int wm = wave>>1, wn = wave&1;
  const int b = m0 >> 9, s0 = m0 & 511;
  #pragma unroll
  for (int pass = 0; pass < 2; ++pass) {
    if (wn == pass) {
      #pragma unroll
      for (int j = 0; j < 4; ++j) {
        const int cl = j*16 + l16;                 // 0..63
        const float bv = bias[n0 + pass*64 + cl];
        #pragma unroll
        for (int i = 0; i < 4; ++i)
          #pragma unroll
          for (int rr = 0; rr < 4; ++rr)
            til[cl*136 + wm*64 + i*16 + quad*4 + rr] = f2b(acc[i][j][rr] + bv);
      }
    }
    __syncthreads();
    const int cl = tid>>2, ck = tid&3;
    const int gn = n0 + pass*64 + cl, h = gn>>6, d = gn&63;
    u16* orow = Vt + ((size_t)((b*8 + h)*64 + d))*512 + s0 + ck*32;
    #pragma unroll
    for (int kk = 0; kk < 4; ++kk)
      *(uint4*)&orow[kk*8] = *(const uint4*)&til[cl*136 + ck*32 + kk*8];
    __syncthreads();
  }
}

// ---------------- projection kernel (7 phases, N=K=512) ----------------
// phases: 0 q(x@Wq *0.125) 1 k(x@Wk) 2 p(bb@.5Wbq +PQs, *0.125)
//         3 m(bb@.5Wbk +PKs) 4 v(vb@Wv +vb residual -> Vt transposed)
//         5 posq(pos@Wpq *0.5 -> PQs) 6 posk(pos@Wpk *0.5 -> PKs)
struct PJ { const u16* A; const u16* W; const float* bias; const u16* ex;
            u16* out; float scale; int exmode; int epiv; };
struct ProjArgs { PJ p[7]; };

__global__ __launch_bounds__(256, 2) void proj_kernel(ProjArgs pa, int phaseBase) {
  __shared__ __align__(16) u16 smem[8704];   // As(4096) Bs(4096); til(8704) reuse
  u16* As = smem;  u16* Bs = smem + 4096;
  const PJ P = pa.p[phaseBase + (blockIdx.x >> 2)];
  const int n0 = (blockIdx.x & 3)*128, m0 = blockIdx.y*128;
  f32x4 acc[4][4] = {};
  kloop(P.A, P.W, m0, n0, 512, 16, As, Bs, P.epiv != 0, acc);
  if (P.epiv) epi_vt(acc, P.bias, P.out, m0, n0, smem);
  else        epi_std(acc, P.bias, P.ex, P.exmode, P.scale, 0, P.out, m0, n0, 512, smem);
}

// ---------------- single GEMM (d-proj, FFN1, FFN2) ----------------
template<int GELU>
__global__ __launch_bounds__(256, 2) void gemm1_kernel(
    const u16* __restrict__ A, const u16* __restrict__ W,
    const float* __restrict__ bias, u16* __restrict__ out, int N, int K)
{
  __shared__ __align__(16) u16 smem[8704];
  const int m0 = blockIdx.y*128, n0 = blockIdx.x*128;
  f32x4 acc[4][4] = {};
  kloop(A, W, m0, n0, K, K>>5, smem, smem + 4096, false, acc);
  epi_std(acc, bias, nullptr, 0, 1.0f, GELU, out, m0, n0, N, smem);
}

// ---------------- cast f32 -> bf16 (all inputs) ----------------
__global__ __launch_bounds__(256) void cast_all_kernel(
    const float* __restrict__ x, const float* __restrict__ v,
    const float* __restrict__ be, const float* __restrict__ pos,
    u16* __restrict__ xb, u16* __restrict__ vb, u16* __restrict__ bb,
    u16* __restrict__ posb)
{
  int z = blockIdx.y;
  const float* in = (z==0) ? x : (z==1) ? v : (z==2) ? be : pos;
  u16* out = (z==0) ? xb : (z==1) ? vb : (z==2) ? bb : posb;
  int n4 = (z < 3) ? (NM*512/4) : (512*512/4);
  int i = blockIdx.x*256 + threadIdx.x;
  if (i >= n4) return;
  float4 w = ((const float4*)in)[i];
  ((ushort4*)out)[i] = make_ushort4(f2b(w.x), f2b(w.y), f2b(w.z), f2b(w.w));
}

// ---------------- weight prep: transpose+cast 10 weights + biases ----------
struct PrepArgs {
  const float* w[10];  // Wq Wk Wv Wpk Wpq Wbk Wbq Wd W1 W2
  u16* o[10];
  const float* bbq; const float* bbk;
  float* Bq2; float* Bk2;
};
__global__ __launch_bounds__(256) void wprep_all_kernel(PrepArgs a) {
  int job = blockIdx.x;
  if (job == 1024) {   // Bq2 = 0.5*bbq ; Bk2 = 0.5*bbk
    for (int i = threadIdx.x; i < 512; i += 256) {
      a.Bq2[i] = 0.5f*a.bbq[i];
      a.Bk2[i] = 0.5f*a.bbk[i];
    }
    return;
  }
  int wsel, n0, k0, K, N;
  if (job < 512)      { wsel = job>>6; int t = job&63;  n0=(t&7)*64;  k0=(t>>3)*64; K=512;  N=512; }
  else if (job < 768) { wsel = 8;      int t = job-512; n0=(t&31)*64; k0=(t>>5)*64; K=512;  N=2048; }
  else                { wsel = 9;      int t = job-768; n0=(t&7)*64;  k0=(t>>3)*64; K=2048; N=512; }
  float sc = (wsel == 5 || wsel == 6) ? 0.5f : 1.0f;    // Wbk, Wbq pre-scaled
  const float* in = a.w[wsel];
  u16* out = a.o[wsel];
  __shared__ __align__(16) u16 til[64*72];
  for (int idx = threadIdx.x; idx < 4096; idx += 256) {
    int r = idx>>6, c = idx&63;
    til[r*72+c] = f2b(in[(size_t)(k0+r)*N + n0+c] * sc);
  }
  __syncthreads();
  for (int idx = threadIdx.x; idx < 4096; idx += 256) {
    int r = idx>>6, c = idx&63;
    out[(size_t)(n0+r)*K + k0+c] = til[c*72+r];
  }
}

// ---------------- flash attention v4 ----------------
// grid (qh=2, h=8, b=32); 512 threads; 2 q-strips/wave = 256 q-rows/block.
// Q-frags: [q+p | q] combined in-register from Qraw/Praw (both pre-scaled /8).
// K-LDS: [k | m] staged from Kraw/Mraw. No-max softmax (masked = exp*1e-30).
__global__ __launch_bounds__(512, 2) void attn_kernel(
    const u16* __restrict__ Qraw, const u16* __restrict__ Praw,
    const u16* __restrict__ Kraw, const u16* __restrict__ Mraw,
    const u16* __restrict__ Vt, const int* __restrict__ iseq,
    u16* __restrict__ ctx)
{
  const int qh = blockIdx.x, h = blockIdx.y, b = blockIdx.z;
  const int tid = threadIdx.x;
  const int wave = tid>>6, lane = tid&63, quad = lane>>4, l16 = lane&15;

  __shared__ __align__(16) u16 Ks[2][64*136];
  __shared__ __align__(16) u16 Vs[2][64*72];
  __shared__ __align__(16) u16 Ps[8][16*72];
  __shared__ float sel[512];

  const int q0 = qh*256;
  const int ntiles = 4*qh + 4;
  const u16* Kg = Kraw + (size_t)(b*512)*512 + h*64;
  const u16* Mg = Mraw + (size_t)(b*512)*512 + h*64;
  const u16* Vg = Vt + (size_t)((b*8 + h)*64)*512;

  if (tid < 512) sel[tid] = (iseq[b*512 + tid] > 0) ? 1.0f : 1e-30f;

  bf16x8 aq[2][4];
  #pragma unroll
  for (int s = 0; s < 2; ++s) {
    const size_t ro = (size_t)(b*512 + q0 + s*128 + wave*16 + l16)*512 + h*64;
    bf16x8 qf0 = *(const bf16x8*)&Qraw[ro + quad*8];
    bf16x8 qf1 = *(const bf16x8*)&Qraw[ro + 32 + quad*8];
    bf16x8 pf0 = *(const bf16x8*)&Praw[ro + quad*8];
    bf16x8 pf1 = *(const bf16x8*)&Praw[ro + 32 + quad*8];
    aq[s][0] = baddv(qf0, pf0); aq[s][1] = baddv(qf1, pf1);
    aq[s][2] = qf0;             aq[s][3] = qf1;
  }

  const int sr = tid>>3, sc8 = (tid&7)*8;
  uint4 kreg = *(const uint4*)&Kg[(size_t)sr*512 + sc8];
  uint4 mreg = *(const uint4*)&Mg[(size_t)sr*512 + sc8];
  uint4 vreg = *(const uint4*)&Vg[(size_t)sr*512 + sc8];

  f32x4 Ob[2][4] = {};
  float lrow[2][4] = {};
  u16* Pw = Ps[wave];
  int buf = 0;

  for (int kt = 0; kt < ntiles; ++kt) {
    const int k0 = kt*64;
    *(uint4*)&Ks[buf][sr*136 + sc8]      = kreg;
    *(uint4*)&Ks[buf][sr*136 + 64 + sc8] = mreg;
    *(uint4*)&Vs[buf][sr*72 + sc8]       = vreg;
    __syncthreads();
    if (kt + 1 < ntiles) {
      const int kn = k0 + 64;
      kreg = *(const uint4*)&Kg[(size_t)(kn + sr)*512 + sc8];
      mreg = *(const uint4*)&Mg[(size_t)(kn + sr)*512 + sc8];
      vreg = *(const uint4*)&Vg[(size_t)sr*512 + kn + sc8];
    }
    const bool act0 = (q0 + wave*16 + 15) >= k0;
    const bool act1 = (q0 + 128 + wave*16 + 15) >= k0;
    if (act1) {
      f32x4 sc[2][4] = {};
      #pragma unroll
      for (int ks = 0; ks < 4; ++ks) {
        bf16x8 bk[4];
        #pragma unroll
        for (int j = 0; j < 4; ++j)
          bk[j] = *(const bf16x8*)&Ks[buf][(j*16 + l16)*136 + ks*32 + quad*8];
        if (act0) {
          #pragma unroll
          for (int j = 0; j < 4; ++j) sc[0][j] = mfma16(aq[0][ks], bk[j], sc[0][j]);
        }
        #pragma unroll
        for (int j = 0; j < 4; ++j) sc[1][j] = mfma16(aq[1][ks], bk[j], sc[1][j]);
      }
      #pragma unroll
      for (int s = 0; s < 2; ++s) {
        if (s == 0 && !act0) continue;
        const int rb = q0 + s*128 + wave*16 + quad*4;
        float pj[4][4];
        #pragma unroll
        for (int j = 0; j < 4; ++j) {
          int col = k0 + j*16 + l16;
          float fs = sel[col];
          #pragma unroll
          for (int r = 0; r < 4; ++r) {
            float m2 = (col <= rb + r) ? fs : 1e-30f;
            pj[j][r] = __expf(sc[s][j][r]) * m2;
          }
        }
        #pragma unroll
        for (int r = 0; r < 4; ++r)
          lrow[s][r] += pj[0][r] + pj[1][r] + pj[2][r] + pj[3][r];
        #pragma unroll
        for (int j = 0; j < 4; ++j)
          #pragma unroll
          for (int r = 0; r < 4; ++r)
            Pw[(quad*4 + r)*72 + j*16 + l16] = f2b(pj[j][r]);
        #pragma unroll
        for (int c = 0; c < 4; ++c) {
          #pragma unroll
          for (int k2 = 0; k2 < 2; ++k2) {
            bf16x8 ap = *(const bf16x8*)&Pw[l16*72 + k2*32 + quad*8];
            bf16x8 bv = *(const bf16x8*)&Vs[buf][(c*16 + l16)*72 + k2*32 + quad*8];
            Ob[s][c] = mfma16(ap, bv, Ob[s][c]);
          }
        }
      }
    }
    buf ^= 1;
  }

  #pragma unroll
  for (int s = 0; s < 2; ++s) {
    #pragma unroll
    for (int r = 0; r < 4; ++r) {
      float l = lrow[s][r];
      #pragma unroll
      for (int d2 = 1; d2 < 16; d2 <<= 1) l += __shfl_xor(l, d2, 64);
      float inv = 1.0f / l;
      int grow = b*512 + q0 + s*128 + wave*16 + quad*4 + r;
      #pragma unroll
      for (int c = 0; c < 4; ++c)
        ctx[(size_t)grow*512 + h*64 + c*16 + l16] = f2b(Ob[s][c][r]*inv);
    }
  }
}

// ---------------- LayerNorm over H=512 (bf16 main input) ----------------
// RES: 0 = f32 residual, 1 = bf16 residual.
template<int RES>
__global__ __launch_bounds__(256) void ln_kernel(
    const u16* __restrict__ a, const void* __restrict__ resv,
    const float* __restrict__ g, const float* __restrict__ be,
    float* __restrict__ of, u16* __restrict__ ob)
{
  const int wave = threadIdx.x >> 6, lane = threadIdx.x & 63;
  const int row = blockIdx.x*4 + wave;
  const ushort4* pa = (const ushort4*)(a + (size_t)row*512);
  ushort4 a0 = pa[lane], a1 = pa[lane+64];
  float v[8] = { b2f(a0.x), b2f(a0.y), b2f(a0.z), b2f(a0.w),
                 b2f(a1.x), b2f(a1.y), b2f(a1.z), b2f(a1.w) };
  if (RES == 1) {
    const ushort4* pr = (const ushort4*)((const u16*)resv + (size_t)row*512);
    ushort4 u0 = pr[lane], u1 = pr[lane+64];
    v[0]+=b2f(u0.x); v[1]+=b2f(u0.y); v[2]+=b2f(u0.z); v[3]+=b2f(u0.w);
    v[4]+=b2f(u1.x); v[5]+=b2f(u1.y); v[6]+=b2f(u1.z); v[7]+=b2f(u1.w);
  } else {
    const float4* pr = (const float4*)((const float*)resv + (size_t)row*512);
    float4 r0 = pr[lane], r1 = pr[lane+64];
    v[0]+=r0.x; v[1]+=r0.y; v[2]+=r0.z; v[3]+=r0.w;
    v[4]+=r1.x; v[5]+=r1.y; v[6]+=r1.z; v[7]+=r1.w;
  }
  float s = 0.f, q = 0.f;
  #pragma unroll
  for (int e = 0; e < 8; ++e) { s += v[e]; q += v[e]*v[e]; }
  #pragma unroll
  for (int d = 1; d < 64; d <<= 1) { s += __shfl_xor(s, d, 64); q += __shfl_xor(q, d, 64); }
  float mean = s * (1.0f/512.0f);
  float var  = q * (1.0f/512.0f) - mean*mean;
  float rstd = rsqrtf(var + 1e-12f);
  float4 g0 = ((const float4*)g)[lane],  g1 = ((const float4*)g)[lane+64];
  float4 b0 = ((const float4*)be)[lane], b1 = ((const float4*)be)[lane+64];
  float o[8];
  o[0]=(v[0]-mean)*rstd*g0.x+b0.x; o[1]=(v[1]-mean)*rstd*g0.y+b0.y;
  o[2]=(v[2]-mean)*rstd*g0.z+b0.z; o[3]=(v[3]-mean)*rstd*g0.w+b0.w;
  o[4]=(v[4]-mean)*rstd*g1.x+b1.x; o[5]=(v[5]-mean)*rstd*g1.y+b1.y;
  o[6]=(v[6]-mean)*rstd*g1.z+b1.z; o[7]=(v[7]-mean)*rstd*g1.w+b1.w;
  if (of) {
    ((float4*)(of + (size_t)row*512))[lane]    = make_float4(o[0],o[1],o[2],o[3]);
    ((float4*)(of + (size_t)row*512))[lane+64] = make_float4(o[4],o[5],o[6],o[7]);
  }
  if (ob) {
    ((ushort4*)(ob + (size_t)row*512))[lane]    = make_ushort4(f2b(o[0]),f2b(o[1]),f2b(o[2]),f2b(o[3]));
    ((ushort4*)(ob + (size_t)row*512))[lane+64] = make_ushort4(f2b(o[4]),f2b(o[5]),f2b(o[6]),f2b(o[7]));
  }
}

// ============================================================================
extern "C" void kernel_launch(void* const* d_in, const int* in_sizes, int n_in,
                              void* d_out, int out_size, void* d_ws, size_t ws_size,
                              hipStream_t stream) {
  (void)in_sizes; (void)n_in; (void)out_size; (void)ws_size;
  const float* x    = (const float*)d_in[0];
  const float* vin  = (const float*)d_in[1];
  const float* beh  = (const float*)d_in[2];
  const float* pos  = (const float*)d_in[3];
  const float* bq   = (const float*)d_in[5];
  const float* bk   = (const float*)d_in[7];
  const float* bv   = (const float*)d_in[9];
  const float* bpk  = (const float*)d_in[11];
  const float* bpq  = (const float*)d_in[13];
  const float* bbk  = (const float*)d_in[15];
  const float* bbq  = (const float*)d_in[17];
  const float* bd   = (const float*)d_in[19];
  const float* ln_g = (const float*)d_in[20];
  const float* ln_b = (const float*)d_in[21];
  const float* b1   = (const float*)d_in[23];
  const float* b2   = (const float*)d_in[25];
  const float* ln2_g= (const float*)d_in[26];
  const float* ln2_b= (const float*)d_in[27];
  const int*   iseq = (const int*)d_in[28];
  float* out = (float*)d_out;
  char* ws = (char*)d_ws;

  // ---- workspace (~145 MB) ----
  size_t off = 0;
  auto nxt = [&](size_t sz) { size_t r = off; off += (sz + 255) & ~(size_t)255; return r; };
  size_t oWT[8]; for (int i = 0; i < 8; ++i) oWT[i] = nxt(512*512*2);
  size_t oW1T = nxt((size_t)512*2048*2);
  size_t oW2T = nxt((size_t)512*2048*2);
  size_t oBq2 = nxt(512*4);
  size_t oBk2 = nxt(512*4);
  size_t oPb  = nxt(512*512*2);
  size_t oPQ  = nxt(512*512*2);           // PQs bf16
  size_t oPK  = nxt(512*512*2);           // PKs bf16
  size_t oXb  = nxt((size_t)NM*512*2);    // xb; dead after proj, reused as ab
  size_t oVb  = nxt((size_t)NM*512*2);    // vb; dead after proj, reused as Cb
  size_t oBb  = nxt((size_t)NM*512*2);    // bb
  size_t oQr  = nxt((size_t)NM*512*2);    // Qraw  (Qr..Mr contiguous 134MB; h1b after attn)
  size_t oPr  = nxt((size_t)NM*512*2);    // Praw
  size_t oKr  = nxt((size_t)NM*512*2);    // Kraw
  size_t oMr  = nxt((size_t)NM*512*2);    // Mraw
  size_t oVt  = nxt((size_t)NM*512*2);    // Vt; dead after attn, reused as f2

  u16* WT[8]; for (int i = 0; i < 8; ++i) WT[i] = (u16*)(ws + oWT[i]);
  u16*   W1T  = (u16*)(ws + oW1T);
  u16*   W2T  = (u16*)(ws + oW2T);
  float* Bq2  = (float*)(ws + oBq2);
  float* Bk2  = (float*)(ws + oBk2);
  u16*   posb = (u16*)(ws + oPb);
  u16*   PQs  = (u16*)(ws + oPQ);
  u16*   PKs  = (u16*)(ws + oPK);
  u16*   xb   = (u16*)(ws + oXb);
  u16*   vb   = (u16*)(ws + oVb);
  u16*   bb   = (u16*)(ws + oBb);
  u16*   Qraw = (u16*)(ws + oQr);
  u16*   Praw = (u16*)(ws + oPr);
  u16*   Kraw = (u16*)(ws + oKr);
  u16*   Mraw = (u16*)(ws + oMr);
  u16*   Vtb  = (u16*)(ws + oVt);
  u16*   Cb   = (u16*)(ws + oVb);   // alias: vb dead after proj
  u16*   db   = (u16*)(ws + oPr);   // alias: Praw dead after attn (LN1 reads before FFN1 writes h1b)
  u16*   ab   = (u16*)(ws + oXb);   // alias: xb dead after proj
  u16*   h1b  = (u16*)(ws + oQr);   // alias: Qraw..Mraw dead after attn (67 MB)
  u16*   f2   = (u16*)(ws + oVt);   // alias: Vt dead after attn

  // 1. casts
  cast_all_kernel<<<dim3(8192, 4), 256, 0, stream>>>(x, vin, beh, pos, xb, vb, bb, posb);
  // 2. weight prep + combined biases
  PrepArgs pr;
  const int wi[10] = {4, 6, 8, 10, 12, 14, 16, 18, 22, 24};
  for (int i = 0; i < 10; ++i) pr.w[i] = (const float*)d_in[wi[i]];
  for (int i = 0; i < 8; ++i)  pr.o[i] = WT[i];
  pr.o[8] = W1T; pr.o[9] = W2T;
  pr.bbq = bbq; pr.bbk = bbk; pr.Bq2 = Bq2; pr.Bk2 = Bk2;
  wprep_all_kernel<<<1025, 256, 0, stream>>>(pr);
  // phase table
  ProjArgs pj;
  pj.p[0] = { xb,   WT[0], bq,   nullptr, Qraw, 0.125f, 0, 0 };
  pj.p[1] = { xb,   WT[1], bk,   nullptr, Kraw, 1.0f,   0, 0 };
  pj.p[2] = { bb,   WT[6], Bq2,  PQs,     Praw, 0.125f, 1, 0 };
  pj.p[3] = { bb,   WT[5], Bk2,  PKs,     Mraw, 1.0f,   1, 0 };
  pj.p[4] = { vb,   WT[2], bv,   nullptr, Vtb,  1.0f,   0, 1 };
  pj.p[5] = { posb, WT[4], bpq,  nullptr, PQs,  0.5f,   0, 0 };
  pj.p[6] = { posb, WT[3], bpk,  nullptr, PKs,  0.5f,   0, 0 };
  // 3. position projections (phases 5,6)
  proj_kernel<<<dim3(8, 4), 256, 0, stream>>>(pj, 5);
  // 4. q,k,p,m,v projections (phases 0..4)
  proj_kernel<<<dim3(20, 128), 256, 0, stream>>>(pj, 0);
  // 5. attention
  attn_kernel<<<dim3(2, 8, 32), 512, 0, stream>>>(Qraw, Praw, Kraw, Mraw, Vtb, iseq, Cb);
  // 6. output projection -> bf16
  gemm1_kernel<0><<<dim3(4, 128), 256, 0, stream>>>(Cb, WT[7], bd, db, 512, 512);
  // 7. LN1 (+ f32 x residual) -> bf16
  ln_kernel<0><<<4096, 256, 0, stream>>>(db, x, ln_g, ln_b, nullptr, ab);
  // 8. FFN1 (gelu) -> bf16
  gemm1_kernel<1><<<dim3(16, 128), 256, 0, stream>>>(ab, W1T, b1, h1b, 2048, 512);
  // 9. FFN2 -> bf16
  gemm1_kernel<0><<<dim3(4, 128), 256, 0, stream>>>(h1b, W2T, b2, f2, 512, 2048);
  // 10. LN2 (+ bf16 attn_out residual) -> f32 out
  ln_kernel<1><<<4096, 256, 0, stream>>>(f2, ab, ln2_g, ln2_b, out, nullptr);
}